// Round 11
// baseline (591.176 us; speedup 1.0000x reference)
//
#include <hip/hip_runtime.h>
#include <hip/hip_fp16.h>
#include <math.h>

#define N_NODES   100000
#define N_EDGES   1000000
#define N_GRAPHS  256
#define NUM_TYPES 200
#define EMB       64
#define HID       32
#define BSHIFT    8
#define BSTRIDE   256
#define NBUCK     391     // ceil(100000/256)
#define EPB       4096
#define NCHUNK    245     // ceil(1e6/4096)
#define MAXBE     4096
#define SRCBITS   17
#define SRCMASK   0x1FFFF
#define THREADS   512
#define GRID      512     // co-residency: 58,368B LDS -> 2 blocks/CU x 256 CU

struct BinBS {                     // 57,940 B
    int srcl[EPB];
    int dstl[EPB];
    unsigned short rank16[EPB];
    unsigned short perm[EPB];
    int cnt[NBUCK];
    int loc[NBUCK];
    int offsL[NBUCK];
    int sA[512];
    int sB[512];
};
struct CsrS {                      // 43,008 B
    int pk[MAXBE];
    unsigned char dl[MAXBE];
    unsigned short rank16[MAXBE];
    unsigned short perm[MAXBE];
    int degL[BSTRIDE];
    int loc[BSTRIDE];
    int sA[512];
    int sB[512];
};

// software grid barrier: all blocks co-resident (grid <= occupancy capacity).
// release fence -> arrive ticket -> spin -> acquire fence (agent scope wb/inv).
__device__ __forceinline__ void gsync(int* bar, int nb) {
    __syncthreads();
    if (threadIdx.x == 0) {
        __threadfence();
        int t = __hip_atomic_fetch_add(bar, 1, __ATOMIC_ACQ_REL, __HIP_MEMORY_SCOPE_AGENT);
        int target = (t / nb + 1) * nb;
        while (__hip_atomic_load(bar, __ATOMIC_RELAXED, __HIP_MEMORY_SCOPE_AGENT) < target)
            __builtin_amdgcn_s_sleep(8);
        __threadfence();
    }
    __syncthreads();
}

__global__ __launch_bounds__(THREADS, 4) void k_mega(
        const int* __restrict__ ids, const int* __restrict__ src,
        const int* __restrict__ dst, const int* __restrict__ batch,
        const float* __restrict__ emb, const float* __restrict__ W1,
        const float* __restrict__ b1, const float* __restrict__ W2,
        const float* __restrict__ b2, const float* __restrict__ Wc1,
        const float* __restrict__ bc1, const float* __restrict__ Wc2,
        const float* __restrict__ bc2, float* __restrict__ out,
        int* bar, int* total, int* counts, int* offs, int* bbase,
        int* binned, int* ssrc, unsigned int* einfo, int2* nodeinfo,
        int* row_ptr, float* dinv, float* table, float* pooled,
        uint2* Y2h, int nb) {
    __shared__ int4 smem4[3648];               // 58,368 B shared by all phases
    char* smem = (char*)smem4;
    int tid = threadIdx.x;
    int gsz = gridDim.x;
    int gtid = blockIdx.x * THREADS + tid;
    int gstride = gsz * THREADS;

    // ---- P0: zero pooled, compute table = emb@W1, binA histogram + bucket totals
    for (int t = gtid; t < N_GRAPHS * HID; t += gstride) pooled[t] = 0.f;
    for (int t = gtid; t < NUM_TYPES * HID; t += gstride) {
        int ty = t >> 5, j = t & 31;
        float s = 0.f;
        for (int k = 0; k < EMB; ++k) s = fmaf(emb[ty * EMB + k], W1[k * HID + j], s);
        table[t] = s;
    }
    {
        int* cnt = (int*)smem;
        for (int c = blockIdx.x; c < NCHUNK; c += gsz) {
            for (int b = tid; b < NBUCK; b += THREADS) cnt[b] = 0;
            __syncthreads();
            int base = c * EPB;
            int n = min(EPB, N_EDGES - base);
            for (int t = tid; t < n; t += THREADS) atomicAdd(&cnt[dst[base + t] >> BSHIFT], 1);
            __syncthreads();
            for (int b = tid; b < NBUCK; b += THREADS) {
                int v = cnt[b];
                counts[c * NBUCK + b] = v;
                if (v) atomicAdd(&total[b], v);
            }
            __syncthreads();
        }
    }
    gsync(bar, nb);

    // ---- P1: block0 scans totals -> bbase; all blocks do per-bucket column scans -> offs (relative)
    {
        int* sA = (int*)smem; int* sB = sA + 512;
        if (blockIdx.x == 0) {
            int v = (tid < NBUCK) ? total[tid] : 0;
            sA[tid] = v;
            __syncthreads();
            int* in = sA; int* ot = sB;
            for (int off = 1; off < 512; off <<= 1) {
                ot[tid] = in[tid] + (tid >= off ? in[tid - off] : 0);
                __syncthreads();
                int* tmp = in; in = ot; ot = tmp;
            }
            if (tid < NBUCK) bbase[tid] = in[tid] - v;
            if (tid == 0) bbase[NBUCK] = N_EDGES;
            __syncthreads();
        }
        for (int b = blockIdx.x; b < NBUCK; b += gsz) {
            int v = (tid < NCHUNK) ? counts[tid * NBUCK + b] : 0;
            sA[tid] = v;
            __syncthreads();
            int* in = sA; int* ot = sB;
            for (int off = 1; off < 512; off <<= 1) {
                ot[tid] = in[tid] + (tid >= off ? in[tid - off] : 0);
                __syncthreads();
                int* tmp = in; in = ot; ot = tmp;
            }
            if (tid < NCHUNK) offs[tid * NBUCK + b] = in[tid] - v;
            __syncthreads();
        }
    }
    gsync(bar, nb);

    // ---- P2: binB — LDS counting-sort by bucket, packed (dlow<<17)|src, coalesced write
    {
        BinBS* S = (BinBS*)smem;
        for (int c = blockIdx.x; c < NCHUNK; c += gsz) {
            int base = c * EPB;
            int n = min(EPB, N_EDGES - base);
            for (int b = tid; b < NBUCK; b += THREADS) {
                S->cnt[b] = 0;
                S->offsL[b] = offs[c * NBUCK + b] + bbase[b];
            }
            __syncthreads();
            for (int t = tid; t < n; t += THREADS) {
                int s = src[base + t], d = dst[base + t];
                S->srcl[t] = s; S->dstl[t] = d;
                S->rank16[t] = (unsigned short)atomicAdd(&S->cnt[d >> BSHIFT], 1);
            }
            __syncthreads();
            for (int t = tid; t < 512; t += THREADS) S->sA[t] = (t < NBUCK) ? S->cnt[t] : 0;
            __syncthreads();
            int* in = S->sA; int* ot = S->sB;
            for (int off = 1; off < 512; off <<= 1) {
                ot[tid] = in[tid] + (tid >= off ? in[tid - off] : 0);
                __syncthreads();
                int* tmp = in; in = ot; ot = tmp;
            }
            for (int b = tid; b < NBUCK; b += THREADS) S->loc[b] = in[b] - S->cnt[b];
            __syncthreads();
            for (int t = tid; t < n; t += THREADS) {
                int b = S->dstl[t] >> BSHIFT;
                S->perm[S->loc[b] + S->rank16[t]] = (unsigned short)t;
            }
            __syncthreads();
            for (int t = tid; t < n; t += THREADS) {
                int e = S->perm[t];
                int d = S->dstl[e], b = d >> BSHIFT;
                int gpos = S->offsL[b] + (t - S->loc[b]);
                binned[gpos] = ((d & (BSTRIDE - 1)) << SRCBITS) | S->srcl[e];
            }
            __syncthreads();
        }
    }
    gsync(bar, nb);

    // ---- P3: csr — per-bucket node sort -> ssrc, row_ptr, dinv, nodeinfo
    {
        CsrS* S = (CsrS*)smem;
        for (int b = blockIdx.x; b < NBUCK; b += gsz) {
            int e0 = bbase[b], e1 = bbase[b + 1];
            int n = min(e1 - e0, MAXBE);
            if (tid < BSTRIDE) S->degL[tid] = 0;
            __syncthreads();
            for (int t = tid; t < n; t += THREADS) {
                int v = binned[e0 + t];
                S->pk[t] = v;
                int d = v >> SRCBITS;
                S->dl[t] = (unsigned char)d;
                S->rank16[t] = (unsigned short)atomicAdd(&S->degL[d], 1);
            }
            __syncthreads();
            if (tid < BSTRIDE) S->sA[tid] = S->degL[tid];
            __syncthreads();
            int* in = S->sA; int* ot = S->sB;
            for (int off = 1; off < BSTRIDE; off <<= 1) {
                if (tid < BSTRIDE) ot[tid] = in[tid] + (tid >= off ? in[tid - off] : 0);
                __syncthreads();
                int* tmp = in; in = ot; ot = tmp;
            }
            if (tid < BSTRIDE) S->loc[tid] = in[tid] - S->degL[tid];
            __syncthreads();
            for (int t = tid; t < n; t += THREADS)
                S->perm[S->loc[S->dl[t]] + S->rank16[t]] = (unsigned short)t;
            __syncthreads();
            for (int t = tid; t < n; t += THREADS)
                ssrc[e0 + t] = S->pk[S->perm[t]] & SRCMASK;
            if (tid < BSTRIDE) {
                int i = b * BSTRIDE + tid;
                if (i < N_NODES) {
                    row_ptr[i] = e0 + S->loc[tid];
                    float dv = rsqrtf((float)S->degL[tid] + 1.0f);
                    dinv[i] = dv;
                    nodeinfo[i] = make_int2(ids[i], __float_as_int(dv));
                }
            }
            if (b == NBUCK - 1 && tid == 0) row_ptr[N_NODES] = N_EDGES;
            __syncthreads();
        }
    }
    gsync(bar, nb);

    // ---- P4: einfo[e] = (ids[src]<<16) | f16bits(dinv[src])
    for (int q = gtid; q < N_EDGES / 4; q += gstride) {
        int e0 = q * 4;
        int4 s4 = *(const int4*)(ssrc + e0);
        int2 n0 = nodeinfo[s4.x], n1 = nodeinfo[s4.y];
        int2 n2 = nodeinfo[s4.z], n3 = nodeinfo[s4.w];
        uint4 r;
        r.x = ((unsigned)n0.x << 16) | __half_as_ushort(__float2half(__int_as_float(n0.y)));
        r.y = ((unsigned)n1.x << 16) | __half_as_ushort(__float2half(__int_as_float(n1.y)));
        r.z = ((unsigned)n2.x << 16) | __half_as_ushort(__float2half(__int_as_float(n2.y)));
        r.w = ((unsigned)n3.x << 16) | __half_as_ushort(__float2half(__int_as_float(n3.y)));
        *(uint4*)(einfo + e0) = r;
    }
    gsync(bar, nb);

    // ---- P5: gather1 — layer1 + relu + W2 GEMM epilogue -> Y2h (f16x4 per lane)
    {
        float* w = (float*)smem;
        for (int k = tid; k < HID * HID; k += THREADS) w[k] = W2[k];
        __syncthreads();
        const float4* tab4 = (const float4*)table;
        const float4* w4 = (const float4*)w;
        for (int u = gtid; u < N_NODES * 8; u += gstride) {
            int i = u >> 3, p = u & 7;
            int s0 = row_ptr[i], n = row_ptr[i + 1] - s0;
            int2 self = nodeinfo[i];
            float di = __int_as_float(self.y);
            float4 acc = tab4[self.x * 8 + p];
            acc.x *= di; acc.y *= di; acc.z *= di; acc.w *= di;
            for (int e = 0; e < n; e += 8) {
                unsigned int ei[8];
#pragma unroll
                for (int uu = 0; uu < 8; ++uu) {
                    int idx = e + uu; idx = (idx > n - 1) ? n - 1 : idx;
                    ei[uu] = einfo[s0 + idx];
                }
#pragma unroll
                for (int uu = 0; uu < 8; ++uu) {
                    float ds = (e + uu < n)
                        ? __half2float(__ushort_as_half((unsigned short)(ei[uu] & 0xFFFF))) : 0.f;
                    float4 v = tab4[(ei[uu] >> 16) * 8 + p];
                    acc.x = fmaf(v.x, ds, acc.x);
                    acc.y = fmaf(v.y, ds, acc.y);
                    acc.z = fmaf(v.z, ds, acc.z);
                    acc.w = fmaf(v.w, ds, acc.w);
                }
            }
            float4 bb = ((const float4*)b1)[p];
            float4 h;
            h.x = fmaxf(fmaf(di, acc.x, bb.x), 0.f);
            h.y = fmaxf(fmaf(di, acc.y, bb.y), 0.f);
            h.z = fmaxf(fmaf(di, acc.z, bb.z), 0.f);
            h.w = fmaxf(fmaf(di, acc.w, bb.w), 0.f);
            float o0 = 0.f, o1 = 0.f, o2 = 0.f, o3 = 0.f;
#pragma unroll
            for (int q = 0; q < 8; ++q) {
                float4 hq;
                hq.x = __shfl(h.x, q, 8);
                hq.y = __shfl(h.y, q, 8);
                hq.z = __shfl(h.z, q, 8);
                hq.w = __shfl(h.w, q, 8);
                float4 w0 = w4[(4 * q + 0) * 8 + p];
                float4 w1 = w4[(4 * q + 1) * 8 + p];
                float4 w2 = w4[(4 * q + 2) * 8 + p];
                float4 w3 = w4[(4 * q + 3) * 8 + p];
                o0 = fmaf(hq.x, w0.x, o0); o1 = fmaf(hq.x, w0.y, o1); o2 = fmaf(hq.x, w0.z, o2); o3 = fmaf(hq.x, w0.w, o3);
                o0 = fmaf(hq.y, w1.x, o0); o1 = fmaf(hq.y, w1.y, o1); o2 = fmaf(hq.y, w1.z, o2); o3 = fmaf(hq.y, w1.w, o3);
                o0 = fmaf(hq.z, w2.x, o0); o1 = fmaf(hq.z, w2.y, o1); o2 = fmaf(hq.z, w2.z, o2); o3 = fmaf(hq.z, w2.w, o3);
                o0 = fmaf(hq.w, w3.x, o0); o1 = fmaf(hq.w, w3.y, o1); o2 = fmaf(hq.w, w3.z, o2); o3 = fmaf(hq.w, w3.w, o3);
            }
            __half2 h01 = __halves2half2(__float2half(o0 * di), __float2half(o1 * di));
            __half2 h23 = __halves2half2(__float2half(o2 * di), __float2half(o3 * di));
            uint2 wv;
            wv.x = *(unsigned int*)&h01;
            wv.y = *(unsigned int*)&h23;
            Y2h[i * 8 + p] = wv;
        }
    }
    gsync(bar, nb);

    // ---- P6: gather2 — layer2 + relu + per-tile pooling partials (tiles of 64 nodes)
    {
        float (*lp)[HID] = (float(*)[HID])smem;      // 64 x 32
        const int NTILE = (N_NODES + 63) / 64;
        for (int T = blockIdx.x; T < NTILE; T += gsz) {
            for (int k = tid; k < 64 * HID; k += THREADS) ((float*)lp)[k] = 0.f;
            __syncthreads();
            int i0 = T * 64;
            int gFirst = batch[i0];
            int i = i0 + (tid >> 3), p = tid & 7;
            if (i < N_NODES) {
                uint2 selfv = Y2h[i * 8 + p];
                float2 sa = __half22float2(*(__half2*)&selfv.x);
                float2 sb = __half22float2(*(__half2*)&selfv.y);
                float4 acc = make_float4(sa.x, sa.y, sb.x, sb.y);
                int s0 = row_ptr[i], n = row_ptr[i + 1] - s0;
                for (int e = 0; e < n; e += 8) {
                    int ss[8];
#pragma unroll
                    for (int uu = 0; uu < 8; ++uu) {
                        int idx = e + uu; idx = (idx > n - 1) ? n - 1 : idx;
                        ss[uu] = ssrc[s0 + idx];
                    }
                    uint2 v[8];
#pragma unroll
                    for (int uu = 0; uu < 8; ++uu) v[uu] = Y2h[ss[uu] * 8 + p];
#pragma unroll
                    for (int uu = 0; uu < 8; ++uu) {
                        float wg = (e + uu < n) ? 1.f : 0.f;
                        float2 fa = __half22float2(*(__half2*)&v[uu].x);
                        float2 fb = __half22float2(*(__half2*)&v[uu].y);
                        acc.x = fmaf(fa.x, wg, acc.x);
                        acc.y = fmaf(fa.y, wg, acc.y);
                        acc.z = fmaf(fb.x, wg, acc.z);
                        acc.w = fmaf(fb.y, wg, acc.w);
                    }
                }
                float di = dinv[i];
                float4 bb = ((const float4*)b2)[p];
                float4 h;
                h.x = fmaxf(fmaf(di, acc.x, bb.x), 0.f);
                h.y = fmaxf(fmaf(di, acc.y, bb.y), 0.f);
                h.z = fmaxf(fmaf(di, acc.z, bb.z), 0.f);
                h.w = fmaxf(fmaf(di, acc.w, bb.w), 0.f);
                int gl = batch[i] - gFirst;              // 0..63 within tile
                atomicAdd(&lp[gl][p * 4 + 0], h.x);
                atomicAdd(&lp[gl][p * 4 + 1], h.y);
                atomicAdd(&lp[gl][p * 4 + 2], h.z);
                atomicAdd(&lp[gl][p * 4 + 3], h.w);
            }
            __syncthreads();
            int iLast = min(i0 + 63, N_NODES - 1);
            int ng = batch[iLast] - gFirst + 1;
            for (int k = tid; k < ng * HID; k += THREADS) {
                int gg = k >> 5, c = k & 31;
                float v = lp[gg][c];
                if (v != 0.f) atomicAdd(&pooled[(gFirst + gg) * HID + c], v);
            }
            __syncthreads();
        }
    }
    gsync(bar, nb);

    // ---- P7: head (block 0)
    if (blockIdx.x == 0 && tid < N_GRAPHS) {
        int g = tid;
        int lo = 0, hi = N_NODES;
        while (lo < hi) { int mid = (lo + hi) >> 1; if (batch[mid] < g) lo = mid + 1; else hi = mid; }
        int start = lo;
        hi = N_NODES;
        while (lo < hi) { int mid = (lo + hi) >> 1; if (batch[mid] < g + 1) lo = mid + 1; else hi = mid; }
        int end = lo;
        float inv = 1.0f / fmaxf((float)(end - start), 1.0f);
        float m[HID];
        for (int j = 0; j < HID; ++j) m[j] = pooled[g * HID + j] * inv;
        float hc[16];
        for (int j = 0; j < 16; ++j) {
            float s = bc1[j];
            for (int k = 0; k < HID; ++k) s = fmaf(m[k], Wc1[k * 16 + j], s);
            hc[j] = fmaxf(s, 0.f);
        }
        float s = bc2[0];
        for (int k = 0; k < 16; ++k) s = fmaf(hc[k], Wc2[k], s);
        out[g] = 1.0f / (1.0f + expf(-s));
    }
}

// ---------------- launch ----------------

extern "C" void kernel_launch(void* const* d_in, const int* in_sizes, int n_in,
                              void* d_out, int out_size, void* d_ws, size_t ws_size,
                              hipStream_t stream) {
    const int*   ids  = (const int*)d_in[0];
    const int*   src  = (const int*)d_in[1];
    const int*   dst  = ((const int*)d_in[1]) + N_EDGES;
    const int*   batch = (const int*)d_in[2];
    const float* emb  = (const float*)d_in[3];
    const float* W1   = (const float*)d_in[4];
    const float* b1   = (const float*)d_in[5];
    const float* W2   = (const float*)d_in[6];
    const float* b2   = (const float*)d_in[7];
    const float* Wc1  = (const float*)d_in[8];
    const float* bc1  = (const float*)d_in[9];
    const float* Wc2  = (const float*)d_in[10];
    const float* bc2  = (const float*)d_in[11];
    float* out = (float*)d_out;

    // workspace layout — all offsets in int elements from base (every section
    // size is a multiple of 4 ints, so 16B alignment is preserved throughout).
    int* W = (int*)d_ws;
    size_t o = 0;
    uint2* Y2h      = (uint2*)(W + o);        o += 1600000;        // 100000*8 uint2
    int*   binned   = W + o;                  o += N_EDGES;        // 1,000,000
    int*   ssrc     = W + o;                  o += N_EDGES;        // 1,000,000
    unsigned int* einfo = (unsigned int*)(W + o); o += N_EDGES;    // 1,000,000
    int2*  nodeinfo = (int2*)(W + o);         o += 2 * N_NODES;    // 200,000
    int*   counts   = W + o;                  o += NCHUNK * NBUCK; // 95,795
    int*   offs     = W + o;                  o += NCHUNK * NBUCK; // 95,795
    int*   bbase    = W + o;                  o += NBUCK + 1;      // 392
    int*   row_ptr  = W + o;                  o += N_NODES + 1;    // 100,001
    o = (o + 3) & ~(size_t)3;                                      // 16B align
    float* dinv     = (float*)(W + o);        o += N_NODES;        // 100,000
    float* table    = (float*)(W + o);        o += NUM_TYPES * HID;// 6,400
    float* pooled   = (float*)(W + o);        o += N_GRAPHS * HID; // 8,192
    int*   ctrl     = W + o;                                       // bar + pad + total[]
    int*   bar      = ctrl;
    int*   total    = ctrl + 4;

    // grid = static co-residency capacity: LDS 58,368B/block -> 2 blocks/CU,
    // launch_bounds(512,4) caps VGPR at 128 -> 16 waves/CU fits. 2 x 256 CU = 512.
    const int grid = GRID;

    (void)hipMemsetAsync(ctrl, 0, (4 + NBUCK) * sizeof(int), stream);
    hipLaunchKernelGGL(k_mega, dim3(grid), dim3(THREADS), 0, stream,
                       ids, src, dst, batch, emb, W1, b1, W2, b2,
                       Wc1, bc1, Wc2, bc2, out,
                       bar, total, counts, offs, bbase,
                       binned, ssrc, einfo, nodeinfo,
                       row_ptr, dinv, table, pooled, Y2h, grid);
}

// Round 12
// 212.784 us; speedup vs baseline: 2.7783x; 2.7783x over previous
//
#include <hip/hip_runtime.h>
#include <hip/hip_fp16.h>
#include <math.h>

#define N_NODES   100000
#define N_EDGES   1000000
#define N_GRAPHS  256
#define NUM_TYPES 200
#define EMB       64
#define HID       32
#define BSHIFT    8
#define BSTRIDE   256
#define NBUCK     391     // ceil(100000/256)
#define EPB       4096
#define NCHUNK    245     // ceil(1e6/4096)
#define MAXBE     4096
#define SRCBITS   17
#define SRCMASK   0x1FFFF

// ---------------- binning -> per-node CSR ----------------

__global__ __launch_bounds__(256) void k_binA(const int* __restrict__ dst,
                                              int* __restrict__ counts) {
    __shared__ int cnt[NBUCK];
    int tid = threadIdx.x, k = blockIdx.x;
    for (int b = tid; b < NBUCK; b += 256) cnt[b] = 0;
    __syncthreads();
    int base = k * EPB;
    int n = min(EPB, N_EDGES - base);
    for (int t = tid; t < n; t += 256) atomicAdd(&cnt[dst[base + t] >> BSHIFT], 1);
    __syncthreads();
    for (int b = tid; b < NBUCK; b += 256) counts[k * NBUCK + b] = cnt[b];
}

// block 0: scan -> offs/bbase; block 1: table = emb@W1; block 2: zero pooled + finish
__global__ __launch_bounds__(512) void k_misc(const int* __restrict__ counts,
                                              int* __restrict__ offs,
                                              int* __restrict__ bbase,
                                              const float* __restrict__ emb,
                                              const float* __restrict__ W1,
                                              float* __restrict__ table,
                                              float* __restrict__ pooled,
                                              int* __restrict__ finish) {
    int tid = threadIdx.x;
    if (blockIdx.x == 0) {
        __shared__ int sA[512], sB[512];
        int total = 0;
        if (tid < NBUCK)
            for (int k = 0; k < NCHUNK; ++k) total += counts[k * NBUCK + tid];
        sA[tid] = (tid < NBUCK) ? total : 0;
        __syncthreads();
        int* in = sA; int* ot = sB;
        for (int off = 1; off < 512; off <<= 1) {
            ot[tid] = in[tid] + (tid >= off ? in[tid - off] : 0);
            __syncthreads();
            int* tmp = in; in = ot; ot = tmp;
        }
        int excl = in[tid] - ((tid < NBUCK) ? total : 0);
        if (tid < NBUCK) {
            bbase[tid] = excl;
            int run = excl;
            for (int k = 0; k < NCHUNK; ++k) {
                offs[k * NBUCK + tid] = run;
                run += counts[k * NBUCK + tid];
            }
        }
        if (tid == 0) bbase[NBUCK] = N_EDGES;
    } else if (blockIdx.x == 1) {
        for (int t = tid; t < NUM_TYPES * HID; t += 512) {
            int ty = t / HID, j = t % HID;
            float s = 0.f;
            for (int k = 0; k < EMB; ++k) s = fmaf(emb[ty * EMB + k], W1[k * HID + j], s);
            table[t] = s;
        }
    } else {
        for (int t = tid; t < N_GRAPHS * HID; t += 512) pooled[t] = 0.f;
        if (tid == 0) *finish = 0;
    }
}

// LDS counting-sort by bucket within each block; packed (dlow<<17)|src output
__global__ __launch_bounds__(512) void k_binB(const int* __restrict__ src,
                                              const int* __restrict__ dst,
                                              const int* __restrict__ offs,
                                              int* __restrict__ binned) {
    __shared__ int srcl[EPB];
    __shared__ int dstl[EPB];
    __shared__ unsigned short rank16[EPB];
    __shared__ unsigned short perm[EPB];
    __shared__ int cnt[NBUCK];
    __shared__ int loc[NBUCK];
    __shared__ int offsL[NBUCK];
    __shared__ int sA[512], sB[512];
    int tid = threadIdx.x, k = blockIdx.x;
    int base = k * EPB;
    int n = min(EPB, N_EDGES - base);
    if (tid < NBUCK) { cnt[tid] = 0; offsL[tid] = offs[k * NBUCK + tid]; }
    __syncthreads();
    for (int t = tid; t < n; t += 512) {
        int s = src[base + t], d = dst[base + t];
        srcl[t] = s; dstl[t] = d;
        rank16[t] = (unsigned short)atomicAdd(&cnt[d >> BSHIFT], 1);
    }
    __syncthreads();
    sA[tid] = (tid < NBUCK) ? cnt[tid] : 0;
    __syncthreads();
    int* in = sA; int* ot = sB;
    for (int off = 1; off < 512; off <<= 1) {
        ot[tid] = in[tid] + (tid >= off ? in[tid - off] : 0);
        __syncthreads();
        int* tmp = in; in = ot; ot = tmp;
    }
    if (tid < NBUCK) loc[tid] = in[tid] - cnt[tid];
    __syncthreads();
    for (int t = tid; t < n; t += 512) {
        int b = dstl[t] >> BSHIFT;
        perm[loc[b] + rank16[t]] = (unsigned short)t;
    }
    __syncthreads();
    for (int t = tid; t < n; t += 512) {
        int e = perm[t];
        int d = dstl[e], b = d >> BSHIFT;
        int gpos = offsL[b] + (t - loc[b]);
        binned[gpos] = ((d & (BSTRIDE - 1)) << SRCBITS) | srcl[e];
    }
}

// one block per bucket: sort by node -> ssrc (coalesced), row_ptr, dinv, nodeinfo
__global__ __launch_bounds__(512) void k_csr(const int* __restrict__ binned,
                                             const int* __restrict__ bbase,
                                             const int* __restrict__ ids,
                                             int* __restrict__ ssrc,
                                             int* __restrict__ row_ptr,
                                             float* __restrict__ dinv,
                                             int2* __restrict__ nodeinfo) {
    __shared__ int pk[MAXBE];
    __shared__ unsigned char dl[MAXBE];
    __shared__ unsigned short rank16[MAXBE];
    __shared__ unsigned short perm[MAXBE];
    __shared__ int degL[BSTRIDE];
    __shared__ int loc[BSTRIDE];
    __shared__ int sA[BSTRIDE], sB[BSTRIDE];
    int tid = threadIdx.x, b = blockIdx.x;
    int e0 = bbase[b], e1 = bbase[b + 1];
    int n = min(e1 - e0, MAXBE);
    if (tid < BSTRIDE) degL[tid] = 0;
    __syncthreads();
    for (int t = tid; t < n; t += 512) {
        int v = binned[e0 + t];
        pk[t] = v;
        int d = v >> SRCBITS;
        dl[t] = (unsigned char)d;
        rank16[t] = (unsigned short)atomicAdd(&degL[d], 1);
    }
    __syncthreads();
    if (tid < BSTRIDE) sA[tid] = degL[tid];
    __syncthreads();
    int* in = sA; int* ot = sB;
    for (int off = 1; off < BSTRIDE; off <<= 1) {
        if (tid < BSTRIDE) ot[tid] = in[tid] + (tid >= off ? in[tid - off] : 0);
        __syncthreads();
        int* tmp = in; in = ot; ot = tmp;
    }
    if (tid < BSTRIDE) loc[tid] = in[tid] - degL[tid];
    __syncthreads();
    for (int t = tid; t < n; t += 512)
        perm[loc[dl[t]] + rank16[t]] = (unsigned short)t;
    __syncthreads();
    for (int t = tid; t < n; t += 512)
        ssrc[e0 + t] = pk[perm[t]] & SRCMASK;
    if (tid < BSTRIDE) {
        int i = b * BSTRIDE + tid;
        if (i < N_NODES) {
            row_ptr[i] = e0 + loc[tid];
            float dv = rsqrtf((float)degL[tid] + 1.0f);
            dinv[i] = dv;
            nodeinfo[i] = make_int2(ids[i], __float_as_int(dv));
        }
    }
    if (b == NBUCK - 1 && tid == 0) row_ptr[N_NODES] = N_EDGES;
}

// per-edge payload precompute: einfo[e] = (ids[src]<<16) | f16bits(dinv[src])
__global__ __launch_bounds__(256) void k_einfo(const int* __restrict__ ssrc,
                                               const int2* __restrict__ nodeinfo,
                                               unsigned int* __restrict__ einfo) {
    int e0 = (blockIdx.x * 256 + threadIdx.x) * 4;
    if (e0 >= N_EDGES) return;
    int4 s4 = *(const int4*)(ssrc + e0);
    int2 n0 = nodeinfo[s4.x], n1 = nodeinfo[s4.y];
    int2 n2 = nodeinfo[s4.z], n3 = nodeinfo[s4.w];
    uint4 r;
    r.x = ((unsigned)n0.x << 16) | __half_as_ushort(__float2half(__int_as_float(n0.y)));
    r.y = ((unsigned)n1.x << 16) | __half_as_ushort(__float2half(__int_as_float(n1.y)));
    r.z = ((unsigned)n2.x << 16) | __half_as_ushort(__float2half(__int_as_float(n2.y)));
    r.w = ((unsigned)n3.x << 16) | __half_as_ushort(__float2half(__int_as_float(n3.y)));
    *(uint4*)(einfo + e0) = r;
}

// ---------------- feature pipeline ----------------

// Layer 1 + layer-2 producer, fused; 8 lanes/node; sequential einfo reads only.
__global__ __launch_bounds__(256) void k_gather1(
        const int2* __restrict__ nodeinfo, const float* __restrict__ table,
        const int* __restrict__ row_ptr, const unsigned int* __restrict__ einfo,
        const float* __restrict__ b1, const float* __restrict__ W2,
        uint2* __restrict__ Y2h) {
    __shared__ float w[HID * HID];
    for (int k = threadIdx.x; k < HID * HID; k += 256) w[k] = W2[k];
    __syncthreads();

    int t = blockIdx.x * 256 + threadIdx.x;          // exact grid: 800000
    int i = t >> 3, p = t & 7;
    const float4* tab4 = (const float4*)table;

    int s0 = row_ptr[i], n = row_ptr[i + 1] - s0;
    int2 self = nodeinfo[i];
    float di = __int_as_float(self.y);
    float4 acc = tab4[self.x * 8 + p];               // self term
    acc.x *= di; acc.y *= di; acc.z *= di; acc.w *= di;

    for (int e = 0; e < n; e += 8) {
        unsigned int ei[8];
#pragma unroll
        for (int u = 0; u < 8; ++u) {
            int idx = e + u; idx = (idx > n - 1) ? n - 1 : idx;
            ei[u] = einfo[s0 + idx];
        }
#pragma unroll
        for (int u = 0; u < 8; ++u) {
            float ds = (e + u < n)
                ? __half2float(__ushort_as_half((unsigned short)(ei[u] & 0xFFFF))) : 0.f;
            float4 v = tab4[(ei[u] >> 16) * 8 + p];
            acc.x = fmaf(v.x, ds, acc.x);
            acc.y = fmaf(v.y, ds, acc.y);
            acc.z = fmaf(v.z, ds, acc.z);
            acc.w = fmaf(v.w, ds, acc.w);
        }
    }
    float4 bb = ((const float4*)b1)[p];
    float4 h;
    h.x = fmaxf(fmaf(di, acc.x, bb.x), 0.f);
    h.y = fmaxf(fmaf(di, acc.y, bb.y), 0.f);
    h.z = fmaxf(fmaf(di, acc.z, bb.z), 0.f);
    h.w = fmaxf(fmaf(di, acc.w, bb.w), 0.f);

    // out[4p+c] = sum_k h[k] * W2[k][4p+c] via intra-8-lane shuffles
    float o0 = 0.f, o1 = 0.f, o2 = 0.f, o3 = 0.f;
    const float4* w4 = (const float4*)w;
#pragma unroll
    for (int q = 0; q < 8; ++q) {
        float4 hq;
        hq.x = __shfl(h.x, q, 8);
        hq.y = __shfl(h.y, q, 8);
        hq.z = __shfl(h.z, q, 8);
        hq.w = __shfl(h.w, q, 8);
        float4 w0 = w4[(4 * q + 0) * 8 + p];
        float4 w1 = w4[(4 * q + 1) * 8 + p];
        float4 w2 = w4[(4 * q + 2) * 8 + p];
        float4 w3 = w4[(4 * q + 3) * 8 + p];
        o0 = fmaf(hq.x, w0.x, o0); o1 = fmaf(hq.x, w0.y, o1); o2 = fmaf(hq.x, w0.z, o2); o3 = fmaf(hq.x, w0.w, o3);
        o0 = fmaf(hq.y, w1.x, o0); o1 = fmaf(hq.y, w1.y, o1); o2 = fmaf(hq.y, w1.z, o2); o3 = fmaf(hq.y, w1.w, o3);
        o0 = fmaf(hq.z, w2.x, o0); o1 = fmaf(hq.z, w2.y, o1); o2 = fmaf(hq.z, w2.z, o2); o3 = fmaf(hq.z, w2.w, o3);
        o0 = fmaf(hq.w, w3.x, o0); o1 = fmaf(hq.w, w3.y, o1); o2 = fmaf(hq.w, w3.z, o2); o3 = fmaf(hq.w, w3.w, o3);
    }
    __half2 h01 = __halves2half2(__float2half(o0 * di), __float2half(o1 * di));
    __half2 h23 = __halves2half2(__float2half(o2 * di), __float2half(o3 * di));
    uint2 wv;
    wv.x = *(unsigned int*)&h01;
    wv.y = *(unsigned int*)&h23;
    Y2h[i * 8 + p] = wv;
}

// Layer 2 (f16 payload) + fused mean-pool; LAST block to finish also runs the head.
__global__ __launch_bounds__(256) void k_gather2(
        const uint2* __restrict__ Y2h, const int* __restrict__ row_ptr,
        const int* __restrict__ ssrc, const float* __restrict__ dinv,
        const float* __restrict__ b2, const int* __restrict__ batch,
        float* __restrict__ pooled, int* __restrict__ finish,
        const float* __restrict__ Wc1, const float* __restrict__ bc1,
        const float* __restrict__ Wc2, const float* __restrict__ bc2,
        float* __restrict__ out) {
    __shared__ float lp[32][HID];                    // per-block per-graph partials
    __shared__ int lastFlag;
    for (int k = threadIdx.x; k < 32 * HID; k += 256) ((float*)lp)[k] = 0.f;
    __syncthreads();

    int t = blockIdx.x * 256 + threadIdx.x;
    int i = t >> 3, p = t & 7;
    int i0 = (blockIdx.x * 256) >> 3;                // first node of block
    int gFirst = batch[i0];

    uint2 selfv = Y2h[i * 8 + p];                    // self term
    float2 sa = __half22float2(*(__half2*)&selfv.x);
    float2 sb = __half22float2(*(__half2*)&selfv.y);
    float4 acc = make_float4(sa.x, sa.y, sb.x, sb.y);

    int s0 = row_ptr[i], n = row_ptr[i + 1] - s0;
    for (int e = 0; e < n; e += 8) {
        int ss[8];
#pragma unroll
        for (int u = 0; u < 8; ++u) {
            int idx = e + u; idx = (idx > n - 1) ? n - 1 : idx;
            ss[u] = ssrc[s0 + idx];
        }
        uint2 v[8];
#pragma unroll
        for (int u = 0; u < 8; ++u) v[u] = Y2h[ss[u] * 8 + p];
#pragma unroll
        for (int u = 0; u < 8; ++u) {
            float wg = (e + u < n) ? 1.f : 0.f;
            float2 fa = __half22float2(*(__half2*)&v[u].x);
            float2 fb = __half22float2(*(__half2*)&v[u].y);
            acc.x = fmaf(fa.x, wg, acc.x);
            acc.y = fmaf(fa.y, wg, acc.y);
            acc.z = fmaf(fb.x, wg, acc.z);
            acc.w = fmaf(fb.y, wg, acc.w);
        }
    }
    float di = dinv[i];
    float4 bb = ((const float4*)b2)[p];
    float4 h;
    h.x = fmaxf(fmaf(di, acc.x, bb.x), 0.f);
    h.y = fmaxf(fmaf(di, acc.y, bb.y), 0.f);
    h.z = fmaxf(fmaf(di, acc.z, bb.z), 0.f);
    h.w = fmaxf(fmaf(di, acc.w, bb.w), 0.f);

    int gl = batch[i] - gFirst;                      // 0..31 within block
    atomicAdd(&lp[gl][p * 4 + 0], h.x);
    atomicAdd(&lp[gl][p * 4 + 1], h.y);
    atomicAdd(&lp[gl][p * 4 + 2], h.z);
    atomicAdd(&lp[gl][p * 4 + 3], h.w);
    __syncthreads();

    int gLast = batch[i0 + 31];
    int ng = gLast - gFirst + 1;
    for (int k = threadIdx.x; k < ng * HID; k += 256) {
        float v = lp[k / HID][k % HID];
        if (v != 0.f) atomicAdd(&pooled[(gFirst + k / HID) * HID + (k % HID)], v);
    }
    __syncthreads();

    // last finished block runs the head (release/acquire via finish counter)
    if (threadIdx.x == 0) {
        __threadfence();
        int d = __hip_atomic_fetch_add(finish, 1, __ATOMIC_ACQ_REL, __HIP_MEMORY_SCOPE_AGENT);
        lastFlag = (d == (int)gridDim.x - 1);
    }
    __syncthreads();
    if (lastFlag) {
        int g = threadIdx.x;                         // 256 threads = 256 graphs
        int lo = 0, hi = N_NODES;
        while (lo < hi) { int mid = (lo + hi) >> 1; if (batch[mid] < g) lo = mid + 1; else hi = mid; }
        int start = lo;
        hi = N_NODES;
        while (lo < hi) { int mid = (lo + hi) >> 1; if (batch[mid] < g + 1) lo = mid + 1; else hi = mid; }
        int end = lo;
        float inv = 1.0f / fmaxf((float)(end - start), 1.0f);
        float m[HID];
        for (int j = 0; j < HID; ++j)
            m[j] = __hip_atomic_load(&pooled[g * HID + j], __ATOMIC_RELAXED,
                                     __HIP_MEMORY_SCOPE_AGENT) * inv;
        float hc[16];
        for (int j = 0; j < 16; ++j) {
            float s = bc1[j];
            for (int k = 0; k < HID; ++k) s = fmaf(m[k], Wc1[k * 16 + j], s);
            hc[j] = fmaxf(s, 0.f);
        }
        float s = bc2[0];
        for (int k = 0; k < 16; ++k) s = fmaf(hc[k], Wc2[k], s);
        out[g] = 1.0f / (1.0f + expf(-s));
    }
}

// ---------------- launch ----------------

extern "C" void kernel_launch(void* const* d_in, const int* in_sizes, int n_in,
                              void* d_out, int out_size, void* d_ws, size_t ws_size,
                              hipStream_t stream) {
    const int*   ids  = (const int*)d_in[0];
    const int*   src  = (const int*)d_in[1];
    const int*   dst  = ((const int*)d_in[1]) + N_EDGES;
    const int*   batch = (const int*)d_in[2];
    const float* emb  = (const float*)d_in[3];
    const float* W1   = (const float*)d_in[4];
    const float* b1   = (const float*)d_in[5];
    const float* W2   = (const float*)d_in[6];
    const float* b2   = (const float*)d_in[7];
    const float* Wc1  = (const float*)d_in[8];
    const float* bc1  = (const float*)d_in[9];
    const float* Wc2  = (const float*)d_in[10];
    const float* bc2  = (const float*)d_in[11];
    float* out = (float*)d_out;

    // workspace layout — int-element offsets from base (all sections multiples
    // of 4 ints -> 16B alignment preserved).
    int* W = (int*)d_ws;
    size_t o = 0;
    uint2* Y2h      = (uint2*)(W + o);        o += 1600000;        // 100000*8 uint2
    int*   binned   = W + o;                  o += N_EDGES;
    int*   ssrc     = W + o;                  o += N_EDGES;
    unsigned int* einfo = (unsigned int*)(W + o); o += N_EDGES;
    int2*  nodeinfo = (int2*)(W + o);         o += 2 * N_NODES;
    int*   counts   = W + o;                  o += NCHUNK * NBUCK;
    int*   offs     = W + o;                  o += NCHUNK * NBUCK;
    int*   bbase    = W + o;                  o += NBUCK + 1;
    int*   row_ptr  = W + o;                  o += N_NODES + 1;
    o = (o + 3) & ~(size_t)3;
    float* dinv     = (float*)(W + o);        o += N_NODES;
    float* table    = (float*)(W + o);        o += NUM_TYPES * HID;
    float* pooled   = (float*)(W + o);        o += N_GRAPHS * HID;
    int*   finish   = W + o;

    const int B = 256;
    const int gNode8 = (N_NODES * 8) / B;       // exact: 3125

    // CSR build via bucket binning (coalesced writes)
    k_binA<<<NCHUNK, B, 0, stream>>>(dst, counts);
    k_misc<<<3, 512, 0, stream>>>(counts, offs, bbase, emb, W1, table, pooled, finish);
    k_binB<<<NCHUNK, 512, 0, stream>>>(src, dst, offs, binned);
    k_csr<<<NBUCK, 512, 0, stream>>>(binned, bbase, ids, ssrc, row_ptr, dinv, nodeinfo);
    k_einfo<<<(N_EDGES / 4 + B - 1) / B, B, 0, stream>>>(ssrc, nodeinfo, einfo);

    // fused layer1 + W2 producer (sequential einfo reads)
    k_gather1<<<gNode8, B, 0, stream>>>(nodeinfo, table, row_ptr, einfo, b1, W2, Y2h);
    // fused layer2 + pooling + head (last block)
    k_gather2<<<gNode8, B, 0, stream>>>((const uint2*)Y2h, row_ptr, ssrc, dinv, b2,
                                        batch, pooled, finish, Wc1, bc1, Wc2, bc2, out);
}

// Round 13
// 120.554 us; speedup vs baseline: 4.9038x; 1.7651x over previous
//
#include <hip/hip_runtime.h>
#include <hip/hip_fp16.h>
#include <math.h>

#define N_NODES   100000
#define N_EDGES   1000000
#define N_GRAPHS  256
#define NUM_TYPES 200
#define EMB       64
#define HID       32
#define BSHIFT    8
#define BSTRIDE   256
#define NBUCK     391     // ceil(100000/256)
#define EPB       4096
#define NCHUNK    245     // ceil(1e6/4096)
#define MAXBE     4096
#define SRCBITS   17
#define SRCMASK   0x1FFFF

// ---------------- binning -> per-node CSR ----------------

__global__ __launch_bounds__(256) void k_binA(const int* __restrict__ dst,
                                              int* __restrict__ counts) {
    __shared__ int cnt[NBUCK];
    int tid = threadIdx.x, k = blockIdx.x;
    for (int b = tid; b < NBUCK; b += 256) cnt[b] = 0;
    __syncthreads();
    int base = k * EPB;
    int n = min(EPB, N_EDGES - base);
    for (int t = tid; t < n; t += 256) atomicAdd(&cnt[dst[base + t] >> BSHIFT], 1);
    __syncthreads();
    for (int b = tid; b < NBUCK; b += 256) counts[k * NBUCK + b] = cnt[b];
}

// block 0: scan -> offs/bbase; block 1: table = emb@W1; block 2: zero pooled
__global__ __launch_bounds__(512) void k_misc(const int* __restrict__ counts,
                                              int* __restrict__ offs,
                                              int* __restrict__ bbase,
                                              const float* __restrict__ emb,
                                              const float* __restrict__ W1,
                                              float* __restrict__ table,
                                              float* __restrict__ pooled) {
    int tid = threadIdx.x;
    if (blockIdx.x == 0) {
        __shared__ int sA[512], sB[512];
        int total = 0;
        if (tid < NBUCK)
            for (int k = 0; k < NCHUNK; ++k) total += counts[k * NBUCK + tid];
        sA[tid] = (tid < NBUCK) ? total : 0;
        __syncthreads();
        int* in = sA; int* ot = sB;
        for (int off = 1; off < 512; off <<= 1) {
            ot[tid] = in[tid] + (tid >= off ? in[tid - off] : 0);
            __syncthreads();
            int* tmp = in; in = ot; ot = tmp;
        }
        int excl = in[tid] - ((tid < NBUCK) ? total : 0);
        if (tid < NBUCK) {
            bbase[tid] = excl;
            int run = excl;
            for (int k = 0; k < NCHUNK; ++k) {
                offs[k * NBUCK + tid] = run;
                run += counts[k * NBUCK + tid];
            }
        }
        if (tid == 0) bbase[NBUCK] = N_EDGES;
    } else if (blockIdx.x == 1) {
        for (int t = tid; t < NUM_TYPES * HID; t += 512) {
            int ty = t / HID, j = t % HID;
            float s = 0.f;
            for (int k = 0; k < EMB; ++k) s = fmaf(emb[ty * EMB + k], W1[k * HID + j], s);
            table[t] = s;
        }
    } else {
        for (int t = tid; t < N_GRAPHS * HID; t += 512) pooled[t] = 0.f;
    }
}

// LDS counting-sort by bucket within each block; packed (dlow<<17)|src output
__global__ __launch_bounds__(512) void k_binB(const int* __restrict__ src,
                                              const int* __restrict__ dst,
                                              const int* __restrict__ offs,
                                              int* __restrict__ binned) {
    __shared__ int srcl[EPB];
    __shared__ int dstl[EPB];
    __shared__ unsigned short rank16[EPB];
    __shared__ unsigned short perm[EPB];
    __shared__ int cnt[NBUCK];
    __shared__ int loc[NBUCK];
    __shared__ int offsL[NBUCK];
    __shared__ int sA[512], sB[512];
    int tid = threadIdx.x, k = blockIdx.x;
    int base = k * EPB;
    int n = min(EPB, N_EDGES - base);
    if (tid < NBUCK) { cnt[tid] = 0; offsL[tid] = offs[k * NBUCK + tid]; }
    __syncthreads();
    for (int t = tid; t < n; t += 512) {
        int s = src[base + t], d = dst[base + t];
        srcl[t] = s; dstl[t] = d;
        rank16[t] = (unsigned short)atomicAdd(&cnt[d >> BSHIFT], 1);
    }
    __syncthreads();
    sA[tid] = (tid < NBUCK) ? cnt[tid] : 0;
    __syncthreads();
    int* in = sA; int* ot = sB;
    for (int off = 1; off < 512; off <<= 1) {
        ot[tid] = in[tid] + (tid >= off ? in[tid - off] : 0);
        __syncthreads();
        int* tmp = in; in = ot; ot = tmp;
    }
    if (tid < NBUCK) loc[tid] = in[tid] - cnt[tid];
    __syncthreads();
    for (int t = tid; t < n; t += 512) {
        int b = dstl[t] >> BSHIFT;
        perm[loc[b] + rank16[t]] = (unsigned short)t;
    }
    __syncthreads();
    for (int t = tid; t < n; t += 512) {
        int e = perm[t];
        int d = dstl[e], b = d >> BSHIFT;
        int gpos = offsL[b] + (t - loc[b]);
        binned[gpos] = ((d & (BSTRIDE - 1)) << SRCBITS) | srcl[e];
    }
}

// one block per bucket: sort by node -> ssrc (coalesced), row_ptr, dinv, nodeinfo
__global__ __launch_bounds__(512) void k_csr(const int* __restrict__ binned,
                                             const int* __restrict__ bbase,
                                             const int* __restrict__ ids,
                                             int* __restrict__ ssrc,
                                             int* __restrict__ row_ptr,
                                             float* __restrict__ dinv,
                                             int2* __restrict__ nodeinfo) {
    __shared__ int pk[MAXBE];
    __shared__ unsigned char dl[MAXBE];
    __shared__ unsigned short rank16[MAXBE];
    __shared__ unsigned short perm[MAXBE];
    __shared__ int degL[BSTRIDE];
    __shared__ int loc[BSTRIDE];
    __shared__ int sA[BSTRIDE], sB[BSTRIDE];
    int tid = threadIdx.x, b = blockIdx.x;
    int e0 = bbase[b], e1 = bbase[b + 1];
    int n = min(e1 - e0, MAXBE);
    if (tid < BSTRIDE) degL[tid] = 0;
    __syncthreads();
    for (int t = tid; t < n; t += 512) {
        int v = binned[e0 + t];
        pk[t] = v;
        int d = v >> SRCBITS;
        dl[t] = (unsigned char)d;
        rank16[t] = (unsigned short)atomicAdd(&degL[d], 1);
    }
    __syncthreads();
    if (tid < BSTRIDE) sA[tid] = degL[tid];
    __syncthreads();
    int* in = sA; int* ot = sB;
    for (int off = 1; off < BSTRIDE; off <<= 1) {
        if (tid < BSTRIDE) ot[tid] = in[tid] + (tid >= off ? in[tid - off] : 0);
        __syncthreads();
        int* tmp = in; in = ot; ot = tmp;
    }
    if (tid < BSTRIDE) loc[tid] = in[tid] - degL[tid];
    __syncthreads();
    for (int t = tid; t < n; t += 512)
        perm[loc[dl[t]] + rank16[t]] = (unsigned short)t;
    __syncthreads();
    for (int t = tid; t < n; t += 512)
        ssrc[e0 + t] = pk[perm[t]] & SRCMASK;
    if (tid < BSTRIDE) {
        int i = b * BSTRIDE + tid;
        if (i < N_NODES) {
            row_ptr[i] = e0 + loc[tid];
            float dv = rsqrtf((float)degL[tid] + 1.0f);
            dinv[i] = dv;
            nodeinfo[i] = make_int2(ids[i], __float_as_int(dv));
        }
    }
    if (b == NBUCK - 1 && tid == 0) row_ptr[N_NODES] = N_EDGES;
}

// per-edge payload precompute: einfo[e] = (ids[src]<<16) | f16bits(dinv[src])
__global__ __launch_bounds__(256) void k_einfo(const int* __restrict__ ssrc,
                                               const int2* __restrict__ nodeinfo,
                                               unsigned int* __restrict__ einfo) {
    int e0 = (blockIdx.x * 256 + threadIdx.x) * 4;
    if (e0 >= N_EDGES) return;
    int4 s4 = *(const int4*)(ssrc + e0);
    int2 n0 = nodeinfo[s4.x], n1 = nodeinfo[s4.y];
    int2 n2 = nodeinfo[s4.z], n3 = nodeinfo[s4.w];
    uint4 r;
    r.x = ((unsigned)n0.x << 16) | __half_as_ushort(__float2half(__int_as_float(n0.y)));
    r.y = ((unsigned)n1.x << 16) | __half_as_ushort(__float2half(__int_as_float(n1.y)));
    r.z = ((unsigned)n2.x << 16) | __half_as_ushort(__float2half(__int_as_float(n2.y)));
    r.w = ((unsigned)n3.x << 16) | __half_as_ushort(__float2half(__int_as_float(n3.y)));
    *(uint4*)(einfo + e0) = r;
}

// ---------------- feature pipeline ----------------

// Layer 1 + layer-2 producer, fused; 8 lanes/node; sequential einfo reads only.
__global__ __launch_bounds__(256) void k_gather1(
        const int2* __restrict__ nodeinfo, const float* __restrict__ table,
        const int* __restrict__ row_ptr, const unsigned int* __restrict__ einfo,
        const float* __restrict__ b1, const float* __restrict__ W2,
        uint2* __restrict__ Y2h) {
    __shared__ float w[HID * HID];
    for (int k = threadIdx.x; k < HID * HID; k += 256) w[k] = W2[k];
    __syncthreads();

    int t = blockIdx.x * 256 + threadIdx.x;          // exact grid: 800000
    int i = t >> 3, p = t & 7;
    const float4* tab4 = (const float4*)table;

    int s0 = row_ptr[i], n = row_ptr[i + 1] - s0;
    int2 self = nodeinfo[i];
    float di = __int_as_float(self.y);
    float4 acc = tab4[self.x * 8 + p];               // self term
    acc.x *= di; acc.y *= di; acc.z *= di; acc.w *= di;

    for (int e = 0; e < n; e += 8) {
        unsigned int ei[8];
#pragma unroll
        for (int u = 0; u < 8; ++u) {
            int idx = e + u; idx = (idx > n - 1) ? n - 1 : idx;
            ei[u] = einfo[s0 + idx];
        }
#pragma unroll
        for (int u = 0; u < 8; ++u) {
            float ds = (e + u < n)
                ? __half2float(__ushort_as_half((unsigned short)(ei[u] & 0xFFFF))) : 0.f;
            float4 v = tab4[(ei[u] >> 16) * 8 + p];
            acc.x = fmaf(v.x, ds, acc.x);
            acc.y = fmaf(v.y, ds, acc.y);
            acc.z = fmaf(v.z, ds, acc.z);
            acc.w = fmaf(v.w, ds, acc.w);
        }
    }
    float4 bb = ((const float4*)b1)[p];
    float4 h;
    h.x = fmaxf(fmaf(di, acc.x, bb.x), 0.f);
    h.y = fmaxf(fmaf(di, acc.y, bb.y), 0.f);
    h.z = fmaxf(fmaf(di, acc.z, bb.z), 0.f);
    h.w = fmaxf(fmaf(di, acc.w, bb.w), 0.f);

    // out[4p+c] = sum_k h[k] * W2[k][4p+c] via intra-8-lane shuffles
    float o0 = 0.f, o1 = 0.f, o2 = 0.f, o3 = 0.f;
    const float4* w4 = (const float4*)w;
#pragma unroll
    for (int q = 0; q < 8; ++q) {
        float4 hq;
        hq.x = __shfl(h.x, q, 8);
        hq.y = __shfl(h.y, q, 8);
        hq.z = __shfl(h.z, q, 8);
        hq.w = __shfl(h.w, q, 8);
        float4 w0 = w4[(4 * q + 0) * 8 + p];
        float4 w1 = w4[(4 * q + 1) * 8 + p];
        float4 w2 = w4[(4 * q + 2) * 8 + p];
        float4 w3 = w4[(4 * q + 3) * 8 + p];
        o0 = fmaf(hq.x, w0.x, o0); o1 = fmaf(hq.x, w0.y, o1); o2 = fmaf(hq.x, w0.z, o2); o3 = fmaf(hq.x, w0.w, o3);
        o0 = fmaf(hq.y, w1.x, o0); o1 = fmaf(hq.y, w1.y, o1); o2 = fmaf(hq.y, w1.z, o2); o3 = fmaf(hq.y, w1.w, o3);
        o0 = fmaf(hq.z, w2.x, o0); o1 = fmaf(hq.z, w2.y, o1); o2 = fmaf(hq.z, w2.z, o2); o3 = fmaf(hq.z, w2.w, o3);
        o0 = fmaf(hq.w, w3.x, o0); o1 = fmaf(hq.w, w3.y, o1); o2 = fmaf(hq.w, w3.z, o2); o3 = fmaf(hq.w, w3.w, o3);
    }
    __half2 h01 = __halves2half2(__float2half(o0 * di), __float2half(o1 * di));
    __half2 h23 = __halves2half2(__float2half(o2 * di), __float2half(o3 * di));
    uint2 wv;
    wv.x = *(unsigned int*)&h01;
    wv.y = *(unsigned int*)&h23;
    Y2h[i * 8 + p] = wv;
}

// Layer 2 (f16 payload) + fused mean-pool partial sums; 8-deep pipelined.
__global__ __launch_bounds__(256) void k_gather2(
        const uint2* __restrict__ Y2h, const int* __restrict__ row_ptr,
        const int* __restrict__ ssrc, const float* __restrict__ dinv,
        const float* __restrict__ b2, const int* __restrict__ batch,
        float* __restrict__ pooled) {
    __shared__ float lp[32][HID];                    // per-block per-graph partials
    for (int k = threadIdx.x; k < 32 * HID; k += 256) ((float*)lp)[k] = 0.f;
    __syncthreads();

    int t = blockIdx.x * 256 + threadIdx.x;
    int i = t >> 3, p = t & 7;
    int i0 = (blockIdx.x * 256) >> 3;                // first node of block
    int gFirst = batch[i0];

    uint2 selfv = Y2h[i * 8 + p];                    // self term
    float2 sa = __half22float2(*(__half2*)&selfv.x);
    float2 sb = __half22float2(*(__half2*)&selfv.y);
    float4 acc = make_float4(sa.x, sa.y, sb.x, sb.y);

    int s0 = row_ptr[i], n = row_ptr[i + 1] - s0;
    for (int e = 0; e < n; e += 8) {
        int ss[8];
#pragma unroll
        for (int u = 0; u < 8; ++u) {
            int idx = e + u; idx = (idx > n - 1) ? n - 1 : idx;
            ss[u] = ssrc[s0 + idx];
        }
        uint2 v[8];
#pragma unroll
        for (int u = 0; u < 8; ++u) v[u] = Y2h[ss[u] * 8 + p];
#pragma unroll
        for (int u = 0; u < 8; ++u) {
            float wg = (e + u < n) ? 1.f : 0.f;
            float2 fa = __half22float2(*(__half2*)&v[u].x);
            float2 fb = __half22float2(*(__half2*)&v[u].y);
            acc.x = fmaf(fa.x, wg, acc.x);
            acc.y = fmaf(fa.y, wg, acc.y);
            acc.z = fmaf(fb.x, wg, acc.z);
            acc.w = fmaf(fb.y, wg, acc.w);
        }
    }
    float di = dinv[i];
    float4 bb = ((const float4*)b2)[p];
    float4 h;
    h.x = fmaxf(fmaf(di, acc.x, bb.x), 0.f);
    h.y = fmaxf(fmaf(di, acc.y, bb.y), 0.f);
    h.z = fmaxf(fmaf(di, acc.z, bb.z), 0.f);
    h.w = fmaxf(fmaf(di, acc.w, bb.w), 0.f);

    int gl = batch[i] - gFirst;                      // 0..31 within block
    atomicAdd(&lp[gl][p * 4 + 0], h.x);
    atomicAdd(&lp[gl][p * 4 + 1], h.y);
    atomicAdd(&lp[gl][p * 4 + 2], h.z);
    atomicAdd(&lp[gl][p * 4 + 3], h.w);
    __syncthreads();

    int gLast = batch[i0 + 31];
    int ng = gLast - gFirst + 1;
    for (int k = threadIdx.x; k < ng * HID; k += 256) {
        float v = lp[k / HID][k % HID];
        if (v != 0.f) atomicAdd(&pooled[(gFirst + k / HID) * HID + (k % HID)], v);
    }
}

// head: mean (counts via binary search) -> relu(@Wc1+bc1) -> sigmoid(@Wc2+bc2)
__global__ void k_head(const float* __restrict__ pooled, const int* __restrict__ batch,
                       const float* __restrict__ Wc1, const float* __restrict__ bc1,
                       const float* __restrict__ Wc2, const float* __restrict__ bc2,
                       float* __restrict__ out) {
    int g = blockIdx.x * blockDim.x + threadIdx.x;
    if (g >= N_GRAPHS) return;
    int lo = 0, hi = N_NODES;
    while (lo < hi) { int mid = (lo + hi) >> 1; if (batch[mid] < g) lo = mid + 1; else hi = mid; }
    int start = lo;
    hi = N_NODES;
    while (lo < hi) { int mid = (lo + hi) >> 1; if (batch[mid] < g + 1) lo = mid + 1; else hi = mid; }
    int end = lo;
    float inv = 1.0f / fmaxf((float)(end - start), 1.0f);
    float m[HID];
    for (int j = 0; j < HID; ++j) m[j] = pooled[g * HID + j] * inv;
    float hc[16];
    for (int j = 0; j < 16; ++j) {
        float s = bc1[j];
        for (int k = 0; k < HID; ++k) s = fmaf(m[k], Wc1[k * 16 + j], s);
        hc[j] = fmaxf(s, 0.f);
    }
    float s = bc2[0];
    for (int k = 0; k < 16; ++k) s = fmaf(hc[k], Wc2[k], s);
    out[g] = 1.0f / (1.0f + expf(-s));
}

// ---------------- launch ----------------

extern "C" void kernel_launch(void* const* d_in, const int* in_sizes, int n_in,
                              void* d_out, int out_size, void* d_ws, size_t ws_size,
                              hipStream_t stream) {
    const int*   ids  = (const int*)d_in[0];
    const int*   src  = (const int*)d_in[1];
    const int*   dst  = ((const int*)d_in[1]) + N_EDGES;
    const int*   batch = (const int*)d_in[2];
    const float* emb  = (const float*)d_in[3];
    const float* W1   = (const float*)d_in[4];
    const float* b1   = (const float*)d_in[5];
    const float* W2   = (const float*)d_in[6];
    const float* b2   = (const float*)d_in[7];
    const float* Wc1  = (const float*)d_in[8];
    const float* bc1  = (const float*)d_in[9];
    const float* Wc2  = (const float*)d_in[10];
    const float* bc2  = (const float*)d_in[11];
    float* out = (float*)d_out;

    // workspace layout — int-element offsets from base (all sections multiples
    // of 4 ints -> 16B alignment preserved).
    int* W = (int*)d_ws;
    size_t o = 0;
    uint2* Y2h      = (uint2*)(W + o);        o += 1600000;        // 100000*8 uint2
    int*   binned   = W + o;                  o += N_EDGES;
    int*   ssrc     = W + o;                  o += N_EDGES;
    unsigned int* einfo = (unsigned int*)(W + o); o += N_EDGES;
    int2*  nodeinfo = (int2*)(W + o);         o += 2 * N_NODES;
    int*   counts   = W + o;                  o += NCHUNK * NBUCK;
    int*   offs     = W + o;                  o += NCHUNK * NBUCK;
    int*   bbase    = W + o;                  o += NBUCK + 1;
    int*   row_ptr  = W + o;                  o += N_NODES + 1;
    o = (o + 3) & ~(size_t)3;
    float* dinv     = (float*)(W + o);        o += N_NODES;
    float* table    = (float*)(W + o);        o += NUM_TYPES * HID;
    float* pooled   = (float*)(W + o);

    const int B = 256;
    const int gNode8 = (N_NODES * 8) / B;       // exact: 3125

    // CSR build via bucket binning (coalesced writes)
    k_binA<<<NCHUNK, B, 0, stream>>>(dst, counts);
    k_misc<<<3, 512, 0, stream>>>(counts, offs, bbase, emb, W1, table, pooled);
    k_binB<<<NCHUNK, 512, 0, stream>>>(src, dst, offs, binned);
    k_csr<<<NBUCK, 512, 0, stream>>>(binned, bbase, ids, ssrc, row_ptr, dinv, nodeinfo);
    k_einfo<<<(N_EDGES / 4 + B - 1) / B, B, 0, stream>>>(ssrc, nodeinfo, einfo);

    // fused layer1 + W2 producer (sequential einfo reads)
    k_gather1<<<gNode8, B, 0, stream>>>(nodeinfo, table, row_ptr, einfo, b1, W2, Y2h);
    // fused layer2 + pooling
    k_gather2<<<gNode8, B, 0, stream>>>((const uint2*)Y2h, row_ptr, ssrc, dinv, b2,
                                        batch, pooled);
    // head
    k_head<<<1, N_GRAPHS, 0, stream>>>(pooled, batch, Wc1, bc1, Wc2, bc2, out);
}

// Round 14
// 117.888 us; speedup vs baseline: 5.0147x; 1.0226x over previous
//
#include <hip/hip_runtime.h>
#include <hip/hip_fp16.h>
#include <math.h>

#define N_NODES   100000
#define N_EDGES   1000000
#define N_GRAPHS  256
#define NUM_TYPES 200
#define EMB       64
#define HID       32
#define BSHIFT    8
#define BSTRIDE   256
#define NBUCK     391     // ceil(100000/256)
#define EPB       4096
#define NCHUNK    245     // ceil(1e6/4096)
#define MAXBE     4096
#define SRCBITS   17
#define SRCMASK   0x1FFFF
#define ELOC      1024    // staged edges per gather1 block (32 nodes, mean 320, +8sigma<500)

// ---------------- binning -> per-node CSR ----------------

__global__ __launch_bounds__(256) void k_binA(const int* __restrict__ dst,
                                              int* __restrict__ counts) {
    __shared__ int cnt[NBUCK];
    int tid = threadIdx.x, k = blockIdx.x;
    for (int b = tid; b < NBUCK; b += 256) cnt[b] = 0;
    __syncthreads();
    int base = k * EPB;
    int n = min(EPB, N_EDGES - base);
    for (int t = tid; t < n; t += 256) atomicAdd(&cnt[dst[base + t] >> BSHIFT], 1);
    __syncthreads();
    for (int b = tid; b < NBUCK; b += 256) counts[k * NBUCK + b] = cnt[b];
}

// block 0: scan -> offs/bbase; block 1: table = emb@W1; block 2: zero pooled
__global__ __launch_bounds__(512) void k_misc(const int* __restrict__ counts,
                                              int* __restrict__ offs,
                                              int* __restrict__ bbase,
                                              const float* __restrict__ emb,
                                              const float* __restrict__ W1,
                                              float* __restrict__ table,
                                              float* __restrict__ pooled) {
    int tid = threadIdx.x;
    if (blockIdx.x == 0) {
        __shared__ int sA[512], sB[512];
        int total = 0;
        if (tid < NBUCK)
            for (int k = 0; k < NCHUNK; ++k) total += counts[k * NBUCK + tid];
        sA[tid] = (tid < NBUCK) ? total : 0;
        __syncthreads();
        int* in = sA; int* ot = sB;
        for (int off = 1; off < 512; off <<= 1) {
            ot[tid] = in[tid] + (tid >= off ? in[tid - off] : 0);
            __syncthreads();
            int* tmp = in; in = ot; ot = tmp;
        }
        int excl = in[tid] - ((tid < NBUCK) ? total : 0);
        if (tid < NBUCK) {
            bbase[tid] = excl;
            int run = excl;
            for (int k = 0; k < NCHUNK; ++k) {
                offs[k * NBUCK + tid] = run;
                run += counts[k * NBUCK + tid];
            }
        }
        if (tid == 0) bbase[NBUCK] = N_EDGES;
    } else if (blockIdx.x == 1) {
        for (int t = tid; t < NUM_TYPES * HID; t += 512) {
            int ty = t / HID, j = t % HID;
            float s = 0.f;
            for (int k = 0; k < EMB; ++k) s = fmaf(emb[ty * EMB + k], W1[k * HID + j], s);
            table[t] = s;
        }
    } else {
        for (int t = tid; t < N_GRAPHS * HID; t += 512) pooled[t] = 0.f;
    }
}

// LDS counting-sort by bucket within each block; packed (dlow<<17)|src output
__global__ __launch_bounds__(512) void k_binB(const int* __restrict__ src,
                                              const int* __restrict__ dst,
                                              const int* __restrict__ offs,
                                              int* __restrict__ binned) {
    __shared__ int srcl[EPB];
    __shared__ int dstl[EPB];
    __shared__ unsigned short rank16[EPB];
    __shared__ unsigned short perm[EPB];
    __shared__ int cnt[NBUCK];
    __shared__ int loc[NBUCK];
    __shared__ int offsL[NBUCK];
    __shared__ int sA[512], sB[512];
    int tid = threadIdx.x, k = blockIdx.x;
    int base = k * EPB;
    int n = min(EPB, N_EDGES - base);
    if (tid < NBUCK) { cnt[tid] = 0; offsL[tid] = offs[k * NBUCK + tid]; }
    __syncthreads();
    for (int t = tid; t < n; t += 512) {
        int s = src[base + t], d = dst[base + t];
        srcl[t] = s; dstl[t] = d;
        rank16[t] = (unsigned short)atomicAdd(&cnt[d >> BSHIFT], 1);
    }
    __syncthreads();
    sA[tid] = (tid < NBUCK) ? cnt[tid] : 0;
    __syncthreads();
    int* in = sA; int* ot = sB;
    for (int off = 1; off < 512; off <<= 1) {
        ot[tid] = in[tid] + (tid >= off ? in[tid - off] : 0);
        __syncthreads();
        int* tmp = in; in = ot; ot = tmp;
    }
    if (tid < NBUCK) loc[tid] = in[tid] - cnt[tid];
    __syncthreads();
    for (int t = tid; t < n; t += 512) {
        int b = dstl[t] >> BSHIFT;
        perm[loc[b] + rank16[t]] = (unsigned short)t;
    }
    __syncthreads();
    for (int t = tid; t < n; t += 512) {
        int e = perm[t];
        int d = dstl[e], b = d >> BSHIFT;
        int gpos = offsL[b] + (t - loc[b]);
        binned[gpos] = ((d & (BSTRIDE - 1)) << SRCBITS) | srcl[e];
    }
}

// one block per bucket: sort by node -> ssrc (coalesced), row_ptr, dinv, nodeinfo
__global__ __launch_bounds__(512) void k_csr(const int* __restrict__ binned,
                                             const int* __restrict__ bbase,
                                             const int* __restrict__ ids,
                                             int* __restrict__ ssrc,
                                             int* __restrict__ row_ptr,
                                             float* __restrict__ dinv,
                                             int2* __restrict__ nodeinfo) {
    __shared__ int pk[MAXBE];
    __shared__ unsigned char dl[MAXBE];
    __shared__ unsigned short rank16[MAXBE];
    __shared__ unsigned short perm[MAXBE];
    __shared__ int degL[BSTRIDE];
    __shared__ int loc[BSTRIDE];
    __shared__ int sA[BSTRIDE], sB[BSTRIDE];
    int tid = threadIdx.x, b = blockIdx.x;
    int e0 = bbase[b], e1 = bbase[b + 1];
    int n = min(e1 - e0, MAXBE);
    if (tid < BSTRIDE) degL[tid] = 0;
    __syncthreads();
    for (int t = tid; t < n; t += 512) {
        int v = binned[e0 + t];
        pk[t] = v;
        int d = v >> SRCBITS;
        dl[t] = (unsigned char)d;
        rank16[t] = (unsigned short)atomicAdd(&degL[d], 1);
    }
    __syncthreads();
    if (tid < BSTRIDE) sA[tid] = degL[tid];
    __syncthreads();
    int* in = sA; int* ot = sB;
    for (int off = 1; off < BSTRIDE; off <<= 1) {
        if (tid < BSTRIDE) ot[tid] = in[tid] + (tid >= off ? in[tid - off] : 0);
        __syncthreads();
        int* tmp = in; in = ot; ot = tmp;
    }
    if (tid < BSTRIDE) loc[tid] = in[tid] - degL[tid];
    __syncthreads();
    for (int t = tid; t < n; t += 512)
        perm[loc[dl[t]] + rank16[t]] = (unsigned short)t;
    __syncthreads();
    for (int t = tid; t < n; t += 512)
        ssrc[e0 + t] = pk[perm[t]] & SRCMASK;
    if (tid < BSTRIDE) {
        int i = b * BSTRIDE + tid;
        if (i < N_NODES) {
            row_ptr[i] = e0 + loc[tid];
            float dv = rsqrtf((float)degL[tid] + 1.0f);
            dinv[i] = dv;
            nodeinfo[i] = make_int2(ids[i], __float_as_int(dv));
        }
    }
    if (b == NBUCK - 1 && tid == 0) row_ptr[N_NODES] = N_EDGES;
}

// ---------------- feature pipeline ----------------

// Layer 1 + layer-2 producer, fused; per-block LDS staging of edge payloads
// (replaces the separate einfo pass), then 8-deep per-node loop.
__global__ __launch_bounds__(256) void k_gather1(
        const int2* __restrict__ nodeinfo, const float* __restrict__ table,
        const int* __restrict__ row_ptr, const int* __restrict__ ssrc,
        const float* __restrict__ b1, const float* __restrict__ W2,
        uint2* __restrict__ Y2h) {
    __shared__ float w[HID * HID];
    __shared__ unsigned int eloc[ELOC];
    int tid = threadIdx.x;
    for (int k = tid; k < HID * HID; k += 256) w[k] = W2[k];

    int i0 = (blockIdx.x * 256) >> 3;                // 32 nodes per block
    int eb0 = row_ptr[i0];
    int eb1 = row_ptr[i0 + 32];                      // sentinel covers i0+32==N_NODES
    int ne = eb1 - eb0;
    bool fits = (ne <= ELOC);
    if (fits) {
        // stage packed payload (ids<<16 | f16(dinv)) with full-block TLP
        for (int t = tid; t < ne; t += 256) {
            int s = ssrc[eb0 + t];
            int2 ni = nodeinfo[s];
            eloc[t] = ((unsigned)ni.x << 16) |
                      __half_as_ushort(__float2half(__int_as_float(ni.y)));
        }
    }
    __syncthreads();

    int t = blockIdx.x * 256 + tid;                  // exact grid: 800000
    int i = t >> 3, p = t & 7;
    const float4* tab4 = (const float4*)table;

    int s0 = row_ptr[i], n = row_ptr[i + 1] - s0;
    int l0 = s0 - eb0;                               // local edge offset in eloc
    int2 self = nodeinfo[i];
    float di = __int_as_float(self.y);
    float4 acc = tab4[self.x * 8 + p];               // self term
    acc.x *= di; acc.y *= di; acc.z *= di; acc.w *= di;

    if (fits) {
        for (int e = 0; e < n; e += 8) {
            unsigned int ei[8];
#pragma unroll
            for (int u = 0; u < 8; ++u) {
                int idx = e + u; idx = (idx > n - 1) ? n - 1 : idx;
                ei[u] = eloc[l0 + idx];
            }
#pragma unroll
            for (int u = 0; u < 8; ++u) {
                float ds = (e + u < n)
                    ? __half2float(__ushort_as_half((unsigned short)(ei[u] & 0xFFFF))) : 0.f;
                float4 v = tab4[(ei[u] >> 16) * 8 + p];
                acc.x = fmaf(v.x, ds, acc.x);
                acc.y = fmaf(v.y, ds, acc.y);
                acc.z = fmaf(v.z, ds, acc.z);
                acc.w = fmaf(v.w, ds, acc.w);
            }
        }
    } else {                                         // fallback (never expected)
        for (int e = 0; e < n; ++e) {
            int s = ssrc[s0 + e];
            int2 ni = nodeinfo[s];
            float ds = __half2float(__float2half(__int_as_float(ni.y)));
            float4 v = tab4[ni.x * 8 + p];
            acc.x = fmaf(v.x, ds, acc.x);
            acc.y = fmaf(v.y, ds, acc.y);
            acc.z = fmaf(v.z, ds, acc.z);
            acc.w = fmaf(v.w, ds, acc.w);
        }
    }
    float4 bb = ((const float4*)b1)[p];
    float4 h;
    h.x = fmaxf(fmaf(di, acc.x, bb.x), 0.f);
    h.y = fmaxf(fmaf(di, acc.y, bb.y), 0.f);
    h.z = fmaxf(fmaf(di, acc.z, bb.z), 0.f);
    h.w = fmaxf(fmaf(di, acc.w, bb.w), 0.f);

    // out[4p+c] = sum_k h[k] * W2[k][4p+c] via intra-8-lane shuffles
    float o0 = 0.f, o1 = 0.f, o2 = 0.f, o3 = 0.f;
    const float4* w4 = (const float4*)w;
#pragma unroll
    for (int q = 0; q < 8; ++q) {
        float4 hq;
        hq.x = __shfl(h.x, q, 8);
        hq.y = __shfl(h.y, q, 8);
        hq.z = __shfl(h.z, q, 8);
        hq.w = __shfl(h.w, q, 8);
        float4 w0 = w4[(4 * q + 0) * 8 + p];
        float4 w1 = w4[(4 * q + 1) * 8 + p];
        float4 w2 = w4[(4 * q + 2) * 8 + p];
        float4 w3 = w4[(4 * q + 3) * 8 + p];
        o0 = fmaf(hq.x, w0.x, o0); o1 = fmaf(hq.x, w0.y, o1); o2 = fmaf(hq.x, w0.z, o2); o3 = fmaf(hq.x, w0.w, o3);
        o0 = fmaf(hq.y, w1.x, o0); o1 = fmaf(hq.y, w1.y, o1); o2 = fmaf(hq.y, w1.z, o2); o3 = fmaf(hq.y, w1.w, o3);
        o0 = fmaf(hq.z, w2.x, o0); o1 = fmaf(hq.z, w2.y, o1); o2 = fmaf(hq.z, w2.z, o2); o3 = fmaf(hq.z, w2.w, o3);
        o0 = fmaf(hq.w, w3.x, o0); o1 = fmaf(hq.w, w3.y, o1); o2 = fmaf(hq.w, w3.z, o2); o3 = fmaf(hq.w, w3.w, o3);
    }
    __half2 h01 = __halves2half2(__float2half(o0 * di), __float2half(o1 * di));
    __half2 h23 = __halves2half2(__float2half(o2 * di), __float2half(o3 * di));
    uint2 wv;
    wv.x = *(unsigned int*)&h01;
    wv.y = *(unsigned int*)&h23;
    Y2h[i * 8 + p] = wv;
}

// Layer 2 (f16 payload) + fused mean-pool partial sums; 8-deep pipelined.
__global__ __launch_bounds__(256) void k_gather2(
        const uint2* __restrict__ Y2h, const int* __restrict__ row_ptr,
        const int* __restrict__ ssrc, const float* __restrict__ dinv,
        const float* __restrict__ b2, const int* __restrict__ batch,
        float* __restrict__ pooled) {
    __shared__ float lp[32][HID];                    // per-block per-graph partials
    for (int k = threadIdx.x; k < 32 * HID; k += 256) ((float*)lp)[k] = 0.f;
    __syncthreads();

    int t = blockIdx.x * 256 + threadIdx.x;
    int i = t >> 3, p = t & 7;
    int i0 = (blockIdx.x * 256) >> 3;                // first node of block
    int gFirst = batch[i0];

    uint2 selfv = Y2h[i * 8 + p];                    // self term
    float2 sa = __half22float2(*(__half2*)&selfv.x);
    float2 sb = __half22float2(*(__half2*)&selfv.y);
    float4 acc = make_float4(sa.x, sa.y, sb.x, sb.y);

    int s0 = row_ptr[i], n = row_ptr[i + 1] - s0;
    for (int e = 0; e < n; e += 8) {
        int ss[8];
#pragma unroll
        for (int u = 0; u < 8; ++u) {
            int idx = e + u; idx = (idx > n - 1) ? n - 1 : idx;
            ss[u] = ssrc[s0 + idx];
        }
        uint2 v[8];
#pragma unroll
        for (int u = 0; u < 8; ++u) v[u] = Y2h[ss[u] * 8 + p];
#pragma unroll
        for (int u = 0; u < 8; ++u) {
            float wg = (e + u < n) ? 1.f : 0.f;
            float2 fa = __half22float2(*(__half2*)&v[u].x);
            float2 fb = __half22float2(*(__half2*)&v[u].y);
            acc.x = fmaf(fa.x, wg, acc.x);
            acc.y = fmaf(fa.y, wg, acc.y);
            acc.z = fmaf(fb.x, wg, acc.z);
            acc.w = fmaf(fb.y, wg, acc.w);
        }
    }
    float di = dinv[i];
    float4 bb = ((const float4*)b2)[p];
    float4 h;
    h.x = fmaxf(fmaf(di, acc.x, bb.x), 0.f);
    h.y = fmaxf(fmaf(di, acc.y, bb.y), 0.f);
    h.z = fmaxf(fmaf(di, acc.z, bb.z), 0.f);
    h.w = fmaxf(fmaf(di, acc.w, bb.w), 0.f);

    int gl = batch[i] - gFirst;                      // 0..31 within block
    atomicAdd(&lp[gl][p * 4 + 0], h.x);
    atomicAdd(&lp[gl][p * 4 + 1], h.y);
    atomicAdd(&lp[gl][p * 4 + 2], h.z);
    atomicAdd(&lp[gl][p * 4 + 3], h.w);
    __syncthreads();

    int gLast = batch[i0 + 31];
    int ng = gLast - gFirst + 1;
    for (int k = threadIdx.x; k < ng * HID; k += 256) {
        float v = lp[k / HID][k % HID];
        if (v != 0.f) atomicAdd(&pooled[(gFirst + k / HID) * HID + (k % HID)], v);
    }
}

// head: mean (counts via binary search) -> relu(@Wc1+bc1) -> sigmoid(@Wc2+bc2)
__global__ void k_head(const float* __restrict__ pooled, const int* __restrict__ batch,
                       const float* __restrict__ Wc1, const float* __restrict__ bc1,
                       const float* __restrict__ Wc2, const float* __restrict__ bc2,
                       float* __restrict__ out) {
    int g = blockIdx.x * blockDim.x + threadIdx.x;
    if (g >= N_GRAPHS) return;
    int lo = 0, hi = N_NODES;
    while (lo < hi) { int mid = (lo + hi) >> 1; if (batch[mid] < g) lo = mid + 1; else hi = mid; }
    int start = lo;
    hi = N_NODES;
    while (lo < hi) { int mid = (lo + hi) >> 1; if (batch[mid] < g + 1) lo = mid + 1; else hi = mid; }
    int end = lo;
    float inv = 1.0f / fmaxf((float)(end - start), 1.0f);
    float m[HID];
    for (int j = 0; j < HID; ++j) m[j] = pooled[g * HID + j] * inv;
    float hc[16];
    for (int j = 0; j < 16; ++j) {
        float s = bc1[j];
        for (int k = 0; k < HID; ++k) s = fmaf(m[k], Wc1[k * 16 + j], s);
        hc[j] = fmaxf(s, 0.f);
    }
    float s = bc2[0];
    for (int k = 0; k < 16; ++k) s = fmaf(hc[k], Wc2[k], s);
    out[g] = 1.0f / (1.0f + expf(-s));
}

// ---------------- launch ----------------

extern "C" void kernel_launch(void* const* d_in, const int* in_sizes, int n_in,
                              void* d_out, int out_size, void* d_ws, size_t ws_size,
                              hipStream_t stream) {
    const int*   ids  = (const int*)d_in[0];
    const int*   src  = (const int*)d_in[1];
    const int*   dst  = ((const int*)d_in[1]) + N_EDGES;
    const int*   batch = (const int*)d_in[2];
    const float* emb  = (const float*)d_in[3];
    const float* W1   = (const float*)d_in[4];
    const float* b1   = (const float*)d_in[5];
    const float* W2   = (const float*)d_in[6];
    const float* b2   = (const float*)d_in[7];
    const float* Wc1  = (const float*)d_in[8];
    const float* bc1  = (const float*)d_in[9];
    const float* Wc2  = (const float*)d_in[10];
    const float* bc2  = (const float*)d_in[11];
    float* out = (float*)d_out;

    // workspace layout — int-element offsets from base (all sections multiples
    // of 4 ints -> 16B alignment preserved).
    int* W = (int*)d_ws;
    size_t o = 0;
    uint2* Y2h      = (uint2*)(W + o);        o += 1600000;        // 100000*8 uint2
    int*   binned   = W + o;                  o += N_EDGES;
    int*   ssrc     = W + o;                  o += N_EDGES;
    int2*  nodeinfo = (int2*)(W + o);         o += 2 * N_NODES;
    int*   counts   = W + o;                  o += NCHUNK * NBUCK;
    int*   offs     = W + o;                  o += NCHUNK * NBUCK;
    int*   bbase    = W + o;                  o += NBUCK + 1;
    int*   row_ptr  = W + o;                  o += N_NODES + 1;
    o = (o + 3) & ~(size_t)3;
    float* dinv     = (float*)(W + o);        o += N_NODES;
    float* table    = (float*)(W + o);        o += NUM_TYPES * HID;
    float* pooled   = (float*)(W + o);

    const int B = 256;
    const int gNode8 = (N_NODES * 8) / B;       // exact: 3125

    // CSR build via bucket binning (coalesced writes)
    k_binA<<<NCHUNK, B, 0, stream>>>(dst, counts);
    k_misc<<<3, 512, 0, stream>>>(counts, offs, bbase, emb, W1, table, pooled);
    k_binB<<<NCHUNK, 512, 0, stream>>>(src, dst, offs, binned);
    k_csr<<<NBUCK, 512, 0, stream>>>(binned, bbase, ids, ssrc, row_ptr, dinv, nodeinfo);

    // fused layer1 + W2 producer (LDS-staged edge payloads)
    k_gather1<<<gNode8, B, 0, stream>>>(nodeinfo, table, row_ptr, ssrc, b1, W2, Y2h);
    // fused layer2 + pooling
    k_gather2<<<gNode8, B, 0, stream>>>((const uint2*)Y2h, row_ptr, ssrc, dinv, b2,
                                        batch, pooled);
    // head
    k_head<<<1, N_GRAPHS, 0, stream>>>(pooled, batch, Wc1, bc1, Wc2, bc2, out);
}

// Round 15
// 104.027 us; speedup vs baseline: 5.6829x; 1.1332x over previous
//
#include <hip/hip_runtime.h>
#include <hip/hip_fp16.h>
#include <math.h>

#define N_NODES   100000
#define N_EDGES   1000000
#define N_GRAPHS  256
#define NUM_TYPES 200
#define EMB       64
#define HID       32
#define BSHIFT    8
#define BSTRIDE   256
#define NBUCK     391     // ceil(100000/256)
#define EPB       4096
#define NCHUNK    245     // ceil(1e6/4096)
#define MAXBE     4096    // padded per-bucket capacity (mean 2560, +30 sigma)
#define SRCBITS   17
#define SRCMASK   0x1FFFF
#define ELOC      1024    // staged edges per gather1 block (32 nodes, mean 320)

// ---------------- phase 1: chunk-local bucket sort (+ table + pooled-zero) ----------------

// blocks 0..NCHUNK-1: sort chunk c's edges by bucket, write chunk-locally at c*EPB
// (no global offsets needed); publish counts[c][b], locg[c][b].
// block NCHUNK: table = emb @ W1.  block NCHUNK+1: zero pooled.
__global__ __launch_bounds__(512) void k_bin(const int* __restrict__ src,
                                             const int* __restrict__ dst,
                                             int* __restrict__ binned,
                                             int* __restrict__ counts,
                                             int* __restrict__ locg,
                                             const float* __restrict__ emb,
                                             const float* __restrict__ W1,
                                             float* __restrict__ table,
                                             float* __restrict__ pooled) {
    int tid = threadIdx.x, c = blockIdx.x;
    if (c == NCHUNK) {
        for (int t = tid; t < NUM_TYPES * HID; t += 512) {
            int ty = t / HID, j = t % HID;
            float s = 0.f;
            for (int k = 0; k < EMB; ++k) s = fmaf(emb[ty * EMB + k], W1[k * HID + j], s);
            table[t] = s;
        }
        return;
    }
    if (c == NCHUNK + 1) {
        for (int t = tid; t < N_GRAPHS * HID; t += 512) pooled[t] = 0.f;
        return;
    }
    __shared__ int srcl[EPB];
    __shared__ int dstl[EPB];
    __shared__ unsigned short rank16[EPB];
    __shared__ unsigned short perm[EPB];
    __shared__ int cnt[NBUCK];
    __shared__ int loc[NBUCK];
    __shared__ int sA[512], sB[512];
    int base = c * EPB;
    int n = min(EPB, N_EDGES - base);
    if (tid < NBUCK) cnt[tid] = 0;
    __syncthreads();
    for (int t = tid; t < n; t += 512) {
        int s = src[base + t], d = dst[base + t];
        srcl[t] = s; dstl[t] = d;
        rank16[t] = (unsigned short)atomicAdd(&cnt[d >> BSHIFT], 1);
    }
    __syncthreads();
    sA[tid] = (tid < NBUCK) ? cnt[tid] : 0;
    __syncthreads();
    int* in = sA; int* ot = sB;
    for (int off = 1; off < 512; off <<= 1) {
        ot[tid] = in[tid] + (tid >= off ? in[tid - off] : 0);
        __syncthreads();
        int* tmp = in; in = ot; ot = tmp;
    }
    if (tid < NBUCK) loc[tid] = in[tid] - cnt[tid];
    __syncthreads();
    for (int t = tid; t < n; t += 512) {
        int b = dstl[t] >> BSHIFT;
        perm[loc[b] + rank16[t]] = (unsigned short)t;
    }
    __syncthreads();
    for (int t = tid; t < n; t += 512) {
        int e = perm[t];
        binned[base + t] = ((dstl[e] & (BSTRIDE - 1)) << SRCBITS) | srcl[e];
    }
    if (tid < NBUCK) {
        counts[c * NBUCK + tid] = cnt[tid];
        locg[c * NBUCK + tid] = loc[tid];
    }
}

// ---------------- phase 2: per-bucket node sort -> padded ssrc + nmeta ----------------

// one block per bucket: gather the bucket's 245 chunk segments into LDS, sort by
// node, write ssrc (padded at b*MAXBE), nodeinfo, and nmeta=(start,deg,ids,dinv).
__global__ __launch_bounds__(512) void k_csr(const int* __restrict__ binned,
                                             const int* __restrict__ counts,
                                             const int* __restrict__ locg,
                                             const int* __restrict__ ids,
                                             int* __restrict__ ssrc,
                                             int2* __restrict__ nodeinfo,
                                             int4* __restrict__ nmeta) {
    __shared__ int pk[MAXBE];
    __shared__ unsigned char dl[MAXBE];
    __shared__ unsigned short rank16[MAXBE];
    __shared__ unsigned short perm[MAXBE];
    __shared__ int degL[BSTRIDE];
    __shared__ int loc[BSTRIDE];
    __shared__ int sA[512], sB[512];
    __shared__ int ccnt[NCHUNK];
    __shared__ int cloc[NCHUNK];
    __shared__ int cbase[NCHUNK];
    int tid = threadIdx.x, b = blockIdx.x;

    // phase A: segment descriptors + scan -> destination offsets in pk
    if (tid < NCHUNK) {
        ccnt[tid] = counts[tid * NBUCK + b];
        cloc[tid] = locg[tid * NBUCK + b];
    }
    __syncthreads();
    sA[tid] = (tid < NCHUNK) ? ccnt[tid] : 0;
    __syncthreads();
    int* in = sA; int* ot = sB;
    for (int off = 1; off < 512; off <<= 1) {
        ot[tid] = in[tid] + (tid >= off ? in[tid - off] : 0);
        __syncthreads();
        int* tmp = in; in = ot; ot = tmp;
    }
    if (tid < NCHUNK) cbase[tid] = in[tid] - ccnt[tid];
    __syncthreads();
    int n = min(in[NCHUNK - 1], MAXBE);   // total edges in bucket
    // copy segments (each ~10 edges) into pk
    for (int c = tid; c < NCHUNK; c += 512) {
        int m = ccnt[c];
        int gsrc = c * EPB + cloc[c];
        int ldst = cbase[c];
        for (int j = 0; j < m; ++j) pk[ldst + j] = binned[gsrc + j];
    }
    if (tid < BSTRIDE) degL[tid] = 0;
    __syncthreads();

    // phase B: node-level counting sort
    for (int t = tid; t < n; t += 512) {
        int d = pk[t] >> SRCBITS;
        dl[t] = (unsigned char)d;
        rank16[t] = (unsigned short)atomicAdd(&degL[d], 1);
    }
    __syncthreads();
    if (tid < BSTRIDE) sA[tid] = degL[tid];
    __syncthreads();
    in = sA; ot = sB;
    for (int off = 1; off < BSTRIDE; off <<= 1) {
        if (tid < BSTRIDE) ot[tid] = in[tid] + (tid >= off ? in[tid - off] : 0);
        __syncthreads();
        int* tmp = in; in = ot; ot = tmp;
    }
    if (tid < BSTRIDE) loc[tid] = in[tid] - degL[tid];
    __syncthreads();
    for (int t = tid; t < n; t += 512)
        perm[loc[dl[t]] + rank16[t]] = (unsigned short)t;
    __syncthreads();
    int e0 = b * MAXBE;
    for (int t = tid; t < n; t += 512)
        ssrc[e0 + t] = pk[perm[t]] & SRCMASK;
    if (tid < BSTRIDE) {
        int i = b * BSTRIDE + tid;
        if (i < N_NODES) {
            float dv = rsqrtf((float)degL[tid] + 1.0f);
            nodeinfo[i] = make_int2(ids[i], __float_as_int(dv));
            nmeta[i] = make_int4(e0 + loc[tid], degL[tid], ids[i], __float_as_int(dv));
        }
    }
}

// ---------------- feature pipeline ----------------

// Layer 1 + layer-2 producer, fused; LDS staging of edge payloads; nmeta int4.
__global__ __launch_bounds__(256) void k_gather1(
        const int2* __restrict__ nodeinfo, const int4* __restrict__ nmeta,
        const float* __restrict__ table, const int* __restrict__ ssrc,
        const float* __restrict__ b1, const float* __restrict__ W2,
        uint2* __restrict__ Y2h) {
    __shared__ float w[HID * HID];
    __shared__ unsigned int eloc[ELOC];
    int tid = threadIdx.x;
    for (int k = tid; k < HID * HID; k += 256) w[k] = W2[k];

    int i0 = (blockIdx.x * 256) >> 3;                // 32 nodes per block (one bucket)
    int4 m0 = nmeta[i0];
    int4 m31 = nmeta[i0 + 31];
    int eb0 = m0.x;
    int ne = m31.x + m31.y - eb0;
    bool fits = (ne <= ELOC);
    if (fits) {
        for (int t = tid; t < ne; t += 256) {
            int s = ssrc[eb0 + t];
            int2 ni = nodeinfo[s];
            eloc[t] = ((unsigned)ni.x << 16) |
                      __half_as_ushort(__float2half(__int_as_float(ni.y)));
        }
    }
    __syncthreads();

    int t = blockIdx.x * 256 + tid;                  // exact grid: 800000
    int i = t >> 3, p = t & 7;
    const float4* tab4 = (const float4*)table;

    int4 nm = nmeta[i];
    int s0 = nm.x, n = nm.y;
    int l0 = s0 - eb0;
    float di = __int_as_float(nm.w);
    float4 acc = tab4[nm.z * 8 + p];                 // self term
    acc.x *= di; acc.y *= di; acc.z *= di; acc.w *= di;

    if (fits) {
        for (int e = 0; e < n; e += 8) {
            unsigned int ei[8];
#pragma unroll
            for (int u = 0; u < 8; ++u) {
                int idx = e + u; idx = (idx > n - 1) ? n - 1 : idx;
                ei[u] = eloc[l0 + idx];
            }
#pragma unroll
            for (int u = 0; u < 8; ++u) {
                float ds = (e + u < n)
                    ? __half2float(__ushort_as_half((unsigned short)(ei[u] & 0xFFFF))) : 0.f;
                float4 v = tab4[(ei[u] >> 16) * 8 + p];
                acc.x = fmaf(v.x, ds, acc.x);
                acc.y = fmaf(v.y, ds, acc.y);
                acc.z = fmaf(v.z, ds, acc.z);
                acc.w = fmaf(v.w, ds, acc.w);
            }
        }
    } else {                                         // fallback (never expected)
        for (int e = 0; e < n; ++e) {
            int s = ssrc[s0 + e];
            int2 ni = nodeinfo[s];
            float ds = __half2float(__float2half(__int_as_float(ni.y)));
            float4 v = tab4[ni.x * 8 + p];
            acc.x = fmaf(v.x, ds, acc.x);
            acc.y = fmaf(v.y, ds, acc.y);
            acc.z = fmaf(v.z, ds, acc.z);
            acc.w = fmaf(v.w, ds, acc.w);
        }
    }
    float4 bb = ((const float4*)b1)[p];
    float4 h;
    h.x = fmaxf(fmaf(di, acc.x, bb.x), 0.f);
    h.y = fmaxf(fmaf(di, acc.y, bb.y), 0.f);
    h.z = fmaxf(fmaf(di, acc.z, bb.z), 0.f);
    h.w = fmaxf(fmaf(di, acc.w, bb.w), 0.f);

    float o0 = 0.f, o1 = 0.f, o2 = 0.f, o3 = 0.f;
    const float4* w4 = (const float4*)w;
#pragma unroll
    for (int q = 0; q < 8; ++q) {
        float4 hq;
        hq.x = __shfl(h.x, q, 8);
        hq.y = __shfl(h.y, q, 8);
        hq.z = __shfl(h.z, q, 8);
        hq.w = __shfl(h.w, q, 8);
        float4 w0 = w4[(4 * q + 0) * 8 + p];
        float4 w1 = w4[(4 * q + 1) * 8 + p];
        float4 w2 = w4[(4 * q + 2) * 8 + p];
        float4 w3 = w4[(4 * q + 3) * 8 + p];
        o0 = fmaf(hq.x, w0.x, o0); o1 = fmaf(hq.x, w0.y, o1); o2 = fmaf(hq.x, w0.z, o2); o3 = fmaf(hq.x, w0.w, o3);
        o0 = fmaf(hq.y, w1.x, o0); o1 = fmaf(hq.y, w1.y, o1); o2 = fmaf(hq.y, w1.z, o2); o3 = fmaf(hq.y, w1.w, o3);
        o0 = fmaf(hq.z, w2.x, o0); o1 = fmaf(hq.z, w2.y, o1); o2 = fmaf(hq.z, w2.z, o2); o3 = fmaf(hq.z, w2.w, o3);
        o0 = fmaf(hq.w, w3.x, o0); o1 = fmaf(hq.w, w3.y, o1); o2 = fmaf(hq.w, w3.z, o2); o3 = fmaf(hq.w, w3.w, o3);
    }
    __half2 h01 = __halves2half2(__float2half(o0 * di), __float2half(o1 * di));
    __half2 h23 = __halves2half2(__float2half(o2 * di), __float2half(o3 * di));
    uint2 wv;
    wv.x = *(unsigned int*)&h01;
    wv.y = *(unsigned int*)&h23;
    Y2h[i * 8 + p] = wv;
}

// Layer 2 (f16 payload) + fused mean-pool partial sums; nmeta int4.
__global__ __launch_bounds__(256) void k_gather2(
        const uint2* __restrict__ Y2h, const int4* __restrict__ nmeta,
        const int* __restrict__ ssrc, const float* __restrict__ b2,
        const int* __restrict__ batch, float* __restrict__ pooled) {
    __shared__ float lp[32][HID];
    for (int k = threadIdx.x; k < 32 * HID; k += 256) ((float*)lp)[k] = 0.f;
    __syncthreads();

    int t = blockIdx.x * 256 + threadIdx.x;
    int i = t >> 3, p = t & 7;
    int i0 = (blockIdx.x * 256) >> 3;
    int gFirst = batch[i0];

    uint2 selfv = Y2h[i * 8 + p];
    float2 sa = __half22float2(*(__half2*)&selfv.x);
    float2 sb = __half22float2(*(__half2*)&selfv.y);
    float4 acc = make_float4(sa.x, sa.y, sb.x, sb.y);

    int4 nm = nmeta[i];
    int s0 = nm.x, n = nm.y;
    for (int e = 0; e < n; e += 8) {
        int ss[8];
#pragma unroll
        for (int u = 0; u < 8; ++u) {
            int idx = e + u; idx = (idx > n - 1) ? n - 1 : idx;
            ss[u] = ssrc[s0 + idx];
        }
        uint2 v[8];
#pragma unroll
        for (int u = 0; u < 8; ++u) v[u] = Y2h[ss[u] * 8 + p];
#pragma unroll
        for (int u = 0; u < 8; ++u) {
            float wg = (e + u < n) ? 1.f : 0.f;
            float2 fa = __half22float2(*(__half2*)&v[u].x);
            float2 fb = __half22float2(*(__half2*)&v[u].y);
            acc.x = fmaf(fa.x, wg, acc.x);
            acc.y = fmaf(fa.y, wg, acc.y);
            acc.z = fmaf(fb.x, wg, acc.z);
            acc.w = fmaf(fb.y, wg, acc.w);
        }
    }
    float di = __int_as_float(nm.w);
    float4 bb = ((const float4*)b2)[p];
    float4 h;
    h.x = fmaxf(fmaf(di, acc.x, bb.x), 0.f);
    h.y = fmaxf(fmaf(di, acc.y, bb.y), 0.f);
    h.z = fmaxf(fmaf(di, acc.z, bb.z), 0.f);
    h.w = fmaxf(fmaf(di, acc.w, bb.w), 0.f);

    int gl = batch[i] - gFirst;
    atomicAdd(&lp[gl][p * 4 + 0], h.x);
    atomicAdd(&lp[gl][p * 4 + 1], h.y);
    atomicAdd(&lp[gl][p * 4 + 2], h.z);
    atomicAdd(&lp[gl][p * 4 + 3], h.w);
    __syncthreads();

    int gLast = batch[i0 + 31];
    int ng = gLast - gFirst + 1;
    for (int k = threadIdx.x; k < ng * HID; k += 256) {
        float v = lp[k / HID][k % HID];
        if (v != 0.f) atomicAdd(&pooled[(gFirst + k / HID) * HID + (k % HID)], v);
    }
}

// head: mean (counts via binary search) -> relu(@Wc1+bc1) -> sigmoid(@Wc2+bc2)
__global__ void k_head(const float* __restrict__ pooled, const int* __restrict__ batch,
                       const float* __restrict__ Wc1, const float* __restrict__ bc1,
                       const float* __restrict__ Wc2, const float* __restrict__ bc2,
                       float* __restrict__ out) {
    int g = blockIdx.x * blockDim.x + threadIdx.x;
    if (g >= N_GRAPHS) return;
    int lo = 0, hi = N_NODES;
    while (lo < hi) { int mid = (lo + hi) >> 1; if (batch[mid] < g) lo = mid + 1; else hi = mid; }
    int start = lo;
    hi = N_NODES;
    while (lo < hi) { int mid = (lo + hi) >> 1; if (batch[mid] < g + 1) lo = mid + 1; else hi = mid; }
    int end = lo;
    float inv = 1.0f / fmaxf((float)(end - start), 1.0f);
    float m[HID];
    for (int j = 0; j < HID; ++j) m[j] = pooled[g * HID + j] * inv;
    float hc[16];
    for (int j = 0; j < 16; ++j) {
        float s = bc1[j];
        for (int k = 0; k < HID; ++k) s = fmaf(m[k], Wc1[k * 16 + j], s);
        hc[j] = fmaxf(s, 0.f);
    }
    float s = bc2[0];
    for (int k = 0; k < 16; ++k) s = fmaf(hc[k], Wc2[k], s);
    out[g] = 1.0f / (1.0f + expf(-s));
}

// ---------------- launch ----------------

extern "C" void kernel_launch(void* const* d_in, const int* in_sizes, int n_in,
                              void* d_out, int out_size, void* d_ws, size_t ws_size,
                              hipStream_t stream) {
    const int*   ids  = (const int*)d_in[0];
    const int*   src  = (const int*)d_in[1];
    const int*   dst  = ((const int*)d_in[1]) + N_EDGES;
    const int*   batch = (const int*)d_in[2];
    const float* emb  = (const float*)d_in[3];
    const float* W1   = (const float*)d_in[4];
    const float* b1   = (const float*)d_in[5];
    const float* W2   = (const float*)d_in[6];
    const float* b2   = (const float*)d_in[7];
    const float* Wc1  = (const float*)d_in[8];
    const float* bc1  = (const float*)d_in[9];
    const float* Wc2  = (const float*)d_in[10];
    const float* bc2  = (const float*)d_in[11];
    float* out = (float*)d_out;

    // workspace layout — int-element offsets; all sections multiples of 4 ints.
    int* W = (int*)d_ws;
    size_t o = 0;
    uint2* Y2h      = (uint2*)(W + o);        o += 1600000;          // 100000*8 uint2
    int*   binned   = W + o;                  o += N_EDGES;          // chunk-local sorted
    int*   ssrc     = W + o;                  o += NBUCK * MAXBE;    // padded per bucket
    int2*  nodeinfo = (int2*)(W + o);         o += 2 * N_NODES;
    int4*  nmeta    = (int4*)(W + o);         o += 4 * N_NODES;
    int*   counts   = W + o;                  o += NCHUNK * NBUCK + 1; // keep mult-of-4 via next
    o = (o + 3) & ~(size_t)3;
    int*   locg     = W + o;                  o += NCHUNK * NBUCK;
    o = (o + 3) & ~(size_t)3;
    float* table    = (float*)(W + o);        o += NUM_TYPES * HID;
    float* pooled   = (float*)(W + o);

    const int B = 256;
    const int gNode8 = (N_NODES * 8) / B;       // exact: 3125

    // phase 1: chunk-local bucket sort (+ table, pooled-zero)
    k_bin<<<NCHUNK + 2, 512, 0, stream>>>(src, dst, binned, counts, locg,
                                          emb, W1, table, pooled);
    // phase 2: per-bucket node sort -> padded ssrc + nmeta
    k_csr<<<NBUCK, 512, 0, stream>>>(binned, counts, locg, ids, ssrc, nodeinfo, nmeta);

    // fused layer1 + W2 producer
    k_gather1<<<gNode8, B, 0, stream>>>(nodeinfo, nmeta, table, ssrc, b1, W2, Y2h);
    // fused layer2 + pooling
    k_gather2<<<gNode8, B, 0, stream>>>((const uint2*)Y2h, nmeta, ssrc, b2, batch, pooled);
    // head
    k_head<<<1, N_GRAPHS, 0, stream>>>(pooled, batch, Wc1, bc1, Wc2, bc2, out);
}